// Round 4
// baseline (1463.173 us; speedup 1.0000x reference)
//
#include <hip/hip_runtime.h>
#include <math.h>

#define NCH 128
#define NGRAPH 128

typedef __attribute__((ext_vector_type(8))) short short8v;
typedef __attribute__((ext_vector_type(4))) float f32x4;

static __device__ __forceinline__ float bf_lo(unsigned u) { return __uint_as_float(u << 16); }
static __device__ __forceinline__ float bf_hi(unsigned u) { return __uint_as_float(u & 0xffff0000u); }
static __device__ __forceinline__ unsigned short f2bf(float f) {
    unsigned u = __float_as_uint(f);
    return (unsigned short)((u + 0x7fffu + ((u >> 16) & 1u)) >> 16);
}

// ---------------- dtype prep ----------------

__global__ void k_cvt(const float* __restrict__ in, unsigned short* __restrict__ outb, long n4) {
    long i = (long)blockIdx.x * 256 + threadIdx.x;
    long stride = (long)gridDim.x * 256;
    for (; i < n4; i += stride) {
        float4 v = *(const float4*)(in + i * 4);
        ushort4 o;
        o.x = f2bf(v.x); o.y = f2bf(v.y); o.z = f2bf(v.z); o.w = f2bf(v.w);
        *(ushort4*)(outb + i * 4) = o;
    }
}

// convW[i][k][n] f32 -> Wt[i][n][k] bf16 (transposed)
__global__ void k_prepw(const float* __restrict__ W, unsigned short* __restrict__ Wt) {
    int idx = blockIdx.x * 256 + threadIdx.x;   // 65536 total
    int i = idx >> 14, rem = idx & 16383;
    int n = rem >> 7, k = rem & 127;
    Wt[idx] = f2bf(W[i * 16384 + k * 128 + n]);
}

// ---------------- CSR build ----------------

__global__ void k_deg(const int* __restrict__ dst, int* __restrict__ deg, int E) {
    int e = blockIdx.x * 256 + threadIdx.x;
    if (e < E) atomicAdd(&deg[dst[e]], 1);
}

__global__ void k_bsum(const int* __restrict__ deg, int* __restrict__ bsum, int n) {
    int tid = threadIdx.x;
    int i0 = blockIdx.x * 1024 + tid * 4;
    int s = 0;
    if (i0 + 3 < n) {
        int4 v = *(const int4*)(deg + i0);
        s = v.x + v.y + v.z + v.w;
    } else {
        for (int j = 0; j < 4; ++j) if (i0 + j < n) s += deg[i0 + j];
    }
    #pragma unroll
    for (int off = 32; off; off >>= 1) s += __shfl_down(s, off);
    __shared__ int ws[4];
    if ((tid & 63) == 0) ws[tid >> 6] = s;
    __syncthreads();
    if (tid == 0) bsum[blockIdx.x] = ws[0] + ws[1] + ws[2] + ws[3];
}

__global__ void k_scan_sums(int* __restrict__ bsum, int nb, int* __restrict__ total_out) {
    int lane = threadIdx.x;
    int carry = 0;
    for (int base = 0; base < nb; base += 64) {
        int v = (base + lane < nb) ? bsum[base + lane] : 0;
        int incl = v;
        #pragma unroll
        for (int off = 1; off < 64; off <<= 1) {
            int t = __shfl_up(incl, off);
            if (lane >= off) incl += t;
        }
        if (base + lane < nb) bsum[base + lane] = carry + incl - v;
        carry += __shfl(incl, 63);
    }
    if (lane == 0) *total_out = carry;
}

__global__ void k_scan_blk(const int* __restrict__ deg, const int* __restrict__ boff,
                           int* __restrict__ rowptr, int n) {
    int tid = threadIdx.x;
    int lane = tid & 63, wave = tid >> 6;
    int i0 = blockIdx.x * 1024 + tid * 4;
    int v0 = 0, v1 = 0, v2 = 0, v3 = 0;
    if (i0 + 3 < n) {
        int4 v = *(const int4*)(deg + i0);
        v0 = v.x; v1 = v.y; v2 = v.z; v3 = v.w;
    } else {
        if (i0 + 0 < n) v0 = deg[i0 + 0];
        if (i0 + 1 < n) v1 = deg[i0 + 1];
        if (i0 + 2 < n) v2 = deg[i0 + 2];
        if (i0 + 3 < n) v3 = deg[i0 + 3];
    }
    int tot = v0 + v1 + v2 + v3;
    int incl = tot;
    #pragma unroll
    for (int off = 1; off < 64; off <<= 1) {
        int t = __shfl_up(incl, off);
        if (lane >= off) incl += t;
    }
    __shared__ int wsum[4];
    if (lane == 63) wsum[wave] = incl;
    __syncthreads();
    int wbase = 0;
    for (int w = 0; w < wave; ++w) wbase += wsum[w];
    int base = boff[blockIdx.x] + wbase + (incl - tot);
    if (i0 + 3 < n) {
        int4 r;
        r.x = base;
        r.y = base + v0;
        r.z = base + v0 + v1;
        r.w = base + v0 + v1 + v2;
        *(int4*)(rowptr + i0) = r;
    } else {
        if (i0 + 0 < n) rowptr[i0 + 0] = base;
        if (i0 + 1 < n) rowptr[i0 + 1] = base + v0;
        if (i0 + 2 < n) rowptr[i0 + 2] = base + v0 + v1;
        if (i0 + 3 < n) rowptr[i0 + 3] = base + v0 + v1 + v2;
    }
}

// ---------------- bucketed fill (bucket = 128 consecutive dst nodes) ----------------
// boff[b] == rowptr[b*128] by construction, so no extra count/scan pass.

__global__ void k_binit(const int* __restrict__ rowptr, int* __restrict__ bcur, int NB) {
    int i = blockIdx.x * 256 + threadIdx.x;
    if (i < NB) bcur[i] = rowptr[i << 7];
}

__global__ void k_bscatter(const int* __restrict__ src, const int* __restrict__ dst,
                           int* __restrict__ bcur, unsigned* __restrict__ ebuf, int E) {
    int e = blockIdx.x * 256 + threadIdx.x;
    if (e < E) {
        int d = dst[e];
        int p = atomicAdd(&bcur[d >> 7], 1);
        ebuf[p] = ((unsigned)src[e] << 7) | (unsigned)(d & 127);
    }
}

__global__ void k_bfill(const unsigned* __restrict__ ebuf, const int* __restrict__ rowptr,
                        int* __restrict__ colarr, int N) {
    __shared__ int cur[128];
    int b = blockIdx.x;
    int nbase = b << 7;
    int ncnt = min(128, N - nbase);
    int tid = threadIdx.x;
    if (tid < ncnt) cur[tid] = rowptr[nbase + tid];
    __syncthreads();
    int lo = rowptr[nbase];
    int hi = rowptr[nbase + ncnt];
    for (int j = lo + tid; j < hi; j += 256) {
        unsigned u = ebuf[j];
        int d = u & 127;
        int pos = atomicAdd(&cur[d], 1);
        colarr[pos] = (int)(u >> 7);
    }
}

// ---------------- fused conv: agg (into LDS) + MFMA GEMM + BN + ReLU ----------------
// 512 threads = 8 waves; tile 64 rows x 128 cols. Wave (wr,wc): rows wr*16..+16,
// cols wc*64..+64. A aggregated into AL (chunk-XOR swizzle), W in WL (XOR swizzle).

__launch_bounds__(512)
__global__ void k_conv(const unsigned short* __restrict__ inb,
                       const int* __restrict__ rowptr, const int* __restrict__ col,
                       const unsigned short* __restrict__ Wt,
                       const float* __restrict__ bias, const float* __restrict__ gamma,
                       const float* __restrict__ beta, const float* __restrict__ mean,
                       const float* __restrict__ var,
                       unsigned short* __restrict__ outb, int N) {
    __shared__ unsigned short WL[128 * 128];   // 32 KB
    __shared__ unsigned short AL[64 * 128];    // 16 KB
    int tid = threadIdx.x;

    // stage Wt -> WL (swizzled: byte ^= (n&7)<<4)
    #pragma unroll
    for (int i = 0; i < 4; ++i) {
        int idx16 = i * 512 + tid;            // 16-byte chunk id, 2048 total
        int n = idx16 >> 4, k8 = idx16 & 15;
        unsigned ba = (unsigned)((n * 256 + k8 * 16) ^ ((n & 7) << 4));
        *(uint4*)((char*)WL + ba) = *(const uint4*)(Wt + n * 128 + k8 * 8);
    }

    // aggregate 64 rows into AL: 16 lanes per row, 16B chunk each, chunk c stored at c^row
    const uint4* in16 = (const uint4*)inb;
    int l = tid & 15;
    #pragma unroll
    for (int rep = 0; rep < 2; ++rep) {
        int rl = rep * 32 + (tid >> 4);
        int row = blockIdx.x * 64 + rl;
        uint4 o = make_uint4(0, 0, 0, 0);
        if (row < N) {
            float acc[8];
            uint4 v = in16[(long)row * 16 + l];
            acc[0] = bf_lo(v.x); acc[1] = bf_hi(v.x);
            acc[2] = bf_lo(v.y); acc[3] = bf_hi(v.y);
            acc[4] = bf_lo(v.z); acc[5] = bf_hi(v.z);
            acc[6] = bf_lo(v.w); acc[7] = bf_hi(v.w);
            int beg = rowptr[row], end = rowptr[row + 1];
            for (int j = beg; j < end; ++j) {
                int s = col[j];
                uint4 u = in16[(long)s * 16 + l];
                acc[0] += bf_lo(u.x); acc[1] += bf_hi(u.x);
                acc[2] += bf_lo(u.y); acc[3] += bf_hi(u.y);
                acc[4] += bf_lo(u.z); acc[5] += bf_hi(u.z);
                acc[6] += bf_lo(u.w); acc[7] += bf_hi(u.w);
            }
            o.x = (unsigned)f2bf(acc[0]) | ((unsigned)f2bf(acc[1]) << 16);
            o.y = (unsigned)f2bf(acc[2]) | ((unsigned)f2bf(acc[3]) << 16);
            o.z = (unsigned)f2bf(acc[4]) | ((unsigned)f2bf(acc[5]) << 16);
            o.w = (unsigned)f2bf(acc[6]) | ((unsigned)f2bf(acc[7]) << 16);
        }
        *(uint4*)((char*)AL + rl * 256 + ((l ^ (rl & 15)) << 4)) = o;
    }
    __syncthreads();

    int wid = tid >> 6, lane = tid & 63;
    int wr = wid & 3, wc = wid >> 2;
    int lr = lane & 15, lg = lane >> 4;
    f32x4 acc[4] = {};
    #pragma unroll
    for (int ks = 0; ks < 4; ++ks) {          // k0 = ks*32
        short8v a = *(const short8v*)((char*)AL + (wr * 16 + lr) * 256 + (((ks * 4 + lg) ^ lr) << 4));
        #pragma unroll
        for (int c = 0; c < 4; ++c) {
            int n = (wc * 4 + c) * 16 + lr;
            unsigned ba = (unsigned)((n * 256 + ks * 64 + lg * 16) ^ ((lr & 7) << 4));
            short8v b = *(const short8v*)((char*)WL + ba);
            acc[c] = __builtin_amdgcn_mfma_f32_16x16x32_bf16(a, b, acc[c], 0, 0, 0);
        }
    }

    // epilogue: lane holds D[wr*16 + lg*4 + r][(wc*4+c)*16 + lr]
    #pragma unroll
    for (int c = 0; c < 4; ++c) {
        int colc = (wc * 4 + c) * 16 + lr;
        float s = gamma[colc] * rsqrtf(var[colc] + 1e-5f);
        float sh = (bias[colc] - mean[colc]) * s + beta[colc];
        #pragma unroll
        for (int r = 0; r < 4; ++r) {
            int row = blockIdx.x * 64 + wr * 16 + lg * 4 + r;
            if (row < N) {
                float v = fmaxf(acc[c][r] * s + sh, 0.f);
                outb[(long)row * NCH + colc] = f2bf(v);
            }
        }
    }
}

// ---------------- global_add_pool (bf16 h, f32 pooled) ----------------

__global__ void k_pool(const unsigned short* __restrict__ h, const int* __restrict__ batch,
                       float* __restrict__ pooled, int sec, int N) {
    int start = blockIdx.x * 128;
    int c2 = threadIdx.x & 63;     // u32 col pair
    int rh = threadIdx.x >> 6;     // 0..3
    const unsigned* h32 = (const unsigned*)h;
    float a0 = 0.f, a1 = 0.f;
    int gcur = -1;
    for (int r = start + rh; r < start + 128; r += 4) {
        if (r >= N) break;
        int g = batch[r];
        if (g != gcur) {
            if (gcur >= 0) {
                atomicAdd(&pooled[gcur * 512 + sec * 128 + c2 * 2 + 0], a0);
                atomicAdd(&pooled[gcur * 512 + sec * 128 + c2 * 2 + 1], a1);
            }
            gcur = g;
            a0 = a1 = 0.f;
        }
        unsigned u = h32[(long)r * 64 + c2];
        a0 += bf_lo(u);
        a1 += bf_hi(u);
    }
    if (gcur >= 0) {
        atomicAdd(&pooled[gcur * 512 + sec * 128 + c2 * 2 + 0], a0);
        atomicAdd(&pooled[gcur * 512 + sec * 128 + c2 * 2 + 1], a1);
    }
}

// ---------------- MLP head + log_softmax ----------------

__launch_bounds__(256)
__global__ void k_mlp(const float* __restrict__ pooled,
                      const float* __restrict__ w1, const float* __restrict__ b1,
                      const float* __restrict__ w2, const float* __restrict__ b2,
                      float* __restrict__ out) {
    __shared__ float row[512];
    __shared__ float hid[256];
    __shared__ float o10[10];
    int g = blockIdx.x, tid = threadIdx.x;
    row[tid] = pooled[g * 512 + tid];
    row[tid + 256] = pooled[g * 512 + 256 + tid];
    __syncthreads();
    float acc = b1[tid];
    for (int k = 0; k < 512; ++k) acc += row[k] * w1[k * 256 + tid];
    hid[tid] = fmaxf(acc, 0.f);
    __syncthreads();
    if (tid < 10) {
        float o = b2[tid];
        for (int k = 0; k < 256; ++k) o += hid[k] * w2[k * 10 + tid];
        o10[tid] = o;
        out[g * 10 + tid] = o;
    }
    __syncthreads();
    if (tid == 0) {
        float m = o10[0];
        for (int j = 1; j < 10; ++j) m = fmaxf(m, o10[j]);
        float s = 0.f;
        for (int j = 0; j < 10; ++j) s += expf(o10[j] - m);
        float ls = m + logf(s);
        for (int j = 0; j < 10; ++j) out[NGRAPH * 10 + g * 10 + j] = o10[j] - ls;
    }
}

// ---------------- launch ----------------

extern "C" void kernel_launch(void* const* d_in, const int* in_sizes, int n_in,
                              void* d_out, int out_size, void* d_ws, size_t ws_size,
                              hipStream_t stream) {
    const float* x     = (const float*)d_in[0];
    const int*   eix   = (const int*)d_in[1];
    const int*   eiy   = (const int*)d_in[2];
    const int*   batch = (const int*)d_in[3];
    const float* convW = (const float*)d_in[4];
    const float* convB = (const float*)d_in[5];
    const float* gma   = (const float*)d_in[6];
    const float* bta   = (const float*)d_in[7];
    const float* mea   = (const float*)d_in[8];
    const float* var   = (const float*)d_in[9];
    const float* w1    = (const float*)d_in[10];
    const float* b1    = (const float*)d_in[11];
    const float* w2    = (const float*)d_in[12];
    const float* b2    = (const float*)d_in[13];
    float* out = (float*)d_out;

    int N = in_sizes[0] / NCH;
    int E = in_sizes[1] / 2;
    int NB = (N + 127) >> 7;         // dst buckets of 128 nodes

    char* p = (char*)d_ws;
    auto alloc = [&](size_t bytes) {
        char* r = p;
        p += (bytes + 255) & ~(size_t)255;
        return r;
    };
    int* rowx     = (int*)alloc((size_t)(N + 1) * 4);
    int* rowy     = (int*)alloc((size_t)(N + 1) * 4);
    int* colx     = (int*)alloc((size_t)E * 4);
    int* coly     = (int*)alloc((size_t)E * 4);
    int* deg      = (int*)alloc((size_t)N * 4);
    int* bsum     = (int*)alloc(4096);
    int* bcur     = (int*)alloc((size_t)NB * 4);
    unsigned* ebuf = (unsigned*)alloc((size_t)E * 4);
    unsigned short* xb   = (unsigned short*)alloc((size_t)N * NCH * 2);
    unsigned short* Wt   = (unsigned short*)alloc((size_t)4 * NCH * NCH * 2);
    unsigned short* bufA = (unsigned short*)alloc((size_t)N * NCH * 2);
    unsigned short* bufB = (unsigned short*)alloc((size_t)N * NCH * 2);
    float* pooled = (float*)alloc((size_t)NGRAPH * 512 * 4);

    const int* srcx = eix;
    const int* dstx = eix + E;
    const int* srcy = eiy;
    const int* dsty = eiy + E;

    int EB = (E + 255) / 256;
    int GB = (N + 63) / 64;          // conv blocks
    int PB = (N + 127) / 128;        // pool blocks
    int NBS = (N + 1023) / 1024;     // scan blocks
    int BIB = (NB + 255) / 256;

    // dtype prep
    k_cvt<<<2048, 256, 0, stream>>>(x, xb, (long)N * 32);
    k_prepw<<<256, 256, 0, stream>>>(convW, Wt);

    // ---- CSR x ----
    hipMemsetAsync(deg, 0, (size_t)N * 4, stream);
    k_deg<<<EB, 256, 0, stream>>>(dstx, deg, E);
    k_bsum<<<NBS, 256, 0, stream>>>(deg, bsum, N);
    k_scan_sums<<<1, 64, 0, stream>>>(bsum, NBS, rowx + N);
    k_scan_blk<<<NBS, 256, 0, stream>>>(deg, bsum, rowx, N);
    k_binit<<<BIB, 256, 0, stream>>>(rowx, bcur, NB);
    k_bscatter<<<EB, 256, 0, stream>>>(srcx, dstx, bcur, ebuf, E);
    k_bfill<<<NB, 256, 0, stream>>>(ebuf, rowx, colx, N);
    // ---- CSR y ----
    hipMemsetAsync(deg, 0, (size_t)N * 4, stream);
    k_deg<<<EB, 256, 0, stream>>>(dsty, deg, E);
    k_bsum<<<NBS, 256, 0, stream>>>(deg, bsum, N);
    k_scan_sums<<<1, 64, 0, stream>>>(bsum, NBS, rowy + N);
    k_scan_blk<<<NBS, 256, 0, stream>>>(deg, bsum, rowy, N);
    k_binit<<<BIB, 256, 0, stream>>>(rowy, bcur, NB);
    k_bscatter<<<EB, 256, 0, stream>>>(srcy, dsty, bcur, ebuf, E);
    k_bfill<<<NB, 256, 0, stream>>>(ebuf, rowy, coly, N);

    hipMemsetAsync(pooled, 0, (size_t)NGRAPH * 512 * 4, stream);

    // conv1_x: xb -> bufA
    k_conv<<<GB, 512, 0, stream>>>(xb, rowx, colx, Wt + 0 * NCH * NCH, convB + 0 * NCH,
                                   gma + 0 * NCH, bta + 0 * NCH, mea + 0 * NCH, var + 0 * NCH,
                                   bufA, N);
    k_pool<<<PB, 256, 0, stream>>>(bufA, batch, pooled, 0, N);

    // conv2_x: bufA -> bufB
    k_conv<<<GB, 512, 0, stream>>>(bufA, rowx, colx, Wt + 1 * NCH * NCH, convB + 1 * NCH,
                                   gma + 1 * NCH, bta + 1 * NCH, mea + 1 * NCH, var + 1 * NCH,
                                   bufB, N);
    k_pool<<<PB, 256, 0, stream>>>(bufB, batch, pooled, 1, N);

    // conv1_y: xb -> bufA
    k_conv<<<GB, 512, 0, stream>>>(xb, rowy, coly, Wt + 2 * NCH * NCH, convB + 2 * NCH,
                                   gma + 2 * NCH, bta + 2 * NCH, mea + 2 * NCH, var + 2 * NCH,
                                   bufA, N);
    k_pool<<<PB, 256, 0, stream>>>(bufA, batch, pooled, 2, N);

    // conv2_y: bufA -> bufB
    k_conv<<<GB, 512, 0, stream>>>(bufA, rowy, coly, Wt + 3 * NCH * NCH, convB + 3 * NCH,
                                   gma + 3 * NCH, bta + 3 * NCH, mea + 3 * NCH, var + 3 * NCH,
                                   bufB, N);
    k_pool<<<PB, 256, 0, stream>>>(bufB, batch, pooled, 3, N);

    // head
    k_mlp<<<NGRAPH, 256, 0, stream>>>(pooled, w1, b1, w2, b2, out);
}

// Round 5
// 758.720 us; speedup vs baseline: 1.9285x; 1.9285x over previous
//
#include <hip/hip_runtime.h>
#include <math.h>

#define NCH 128
#define NGRAPH 128
#define BSH 9                 // bucket shift: 512 nodes per bucket
#define BSZ (1 << BSH)

typedef __attribute__((ext_vector_type(8))) short short8v;
typedef __attribute__((ext_vector_type(4))) float f32x4;

static __device__ __forceinline__ float bf_lo(unsigned u) { return __uint_as_float(u << 16); }
static __device__ __forceinline__ float bf_hi(unsigned u) { return __uint_as_float(u & 0xffff0000u); }
static __device__ __forceinline__ unsigned short f2bf(float f) {
    unsigned u = __float_as_uint(f);
    return (unsigned short)((u + 0x7fffu + ((u >> 16) & 1u)) >> 16);
}

// ---------------- dtype prep ----------------

__global__ void k_cvt(const float* __restrict__ in, unsigned short* __restrict__ outb, long n4) {
    long i = (long)blockIdx.x * 256 + threadIdx.x;
    long stride = (long)gridDim.x * 256;
    for (; i < n4; i += stride) {
        float4 v = *(const float4*)(in + i * 4);
        ushort4 o;
        o.x = f2bf(v.x); o.y = f2bf(v.y); o.z = f2bf(v.z); o.w = f2bf(v.w);
        *(ushort4*)(outb + i * 4) = o;
    }
}

// convW[i][k][n] f32 -> Wt[i][n][k] bf16 (transposed)
__global__ void k_prepw(const float* __restrict__ W, unsigned short* __restrict__ Wt) {
    int idx = blockIdx.x * 256 + threadIdx.x;   // 65536 total
    int i = idx >> 14, rem = idx & 16383;
    int n = rem >> 7, k = rem & 127;
    Wt[idx] = f2bf(W[i * 16384 + k * 128 + n]);
}

// ---------------- CSR build ----------------

__global__ void k_deg(const int* __restrict__ dst, int* __restrict__ deg, int E) {
    int e = blockIdx.x * 256 + threadIdx.x;
    if (e < E) atomicAdd(&deg[dst[e]], 1);
}

__global__ void k_bsum(const int* __restrict__ deg, int* __restrict__ bsum, int n) {
    int tid = threadIdx.x;
    int i0 = blockIdx.x * 1024 + tid * 4;
    int s = 0;
    if (i0 + 3 < n) {
        int4 v = *(const int4*)(deg + i0);
        s = v.x + v.y + v.z + v.w;
    } else {
        for (int j = 0; j < 4; ++j) if (i0 + j < n) s += deg[i0 + j];
    }
    #pragma unroll
    for (int off = 32; off; off >>= 1) s += __shfl_down(s, off);
    __shared__ int ws[4];
    if ((tid & 63) == 0) ws[tid >> 6] = s;
    __syncthreads();
    if (tid == 0) bsum[blockIdx.x] = ws[0] + ws[1] + ws[2] + ws[3];
}

__global__ void k_scan_sums(int* __restrict__ bsum, int nb, int* __restrict__ total_out) {
    int lane = threadIdx.x;
    int carry = 0;
    for (int base = 0; base < nb; base += 64) {
        int v = (base + lane < nb) ? bsum[base + lane] : 0;
        int incl = v;
        #pragma unroll
        for (int off = 1; off < 64; off <<= 1) {
            int t = __shfl_up(incl, off);
            if (lane >= off) incl += t;
        }
        if (base + lane < nb) bsum[base + lane] = carry + incl - v;
        carry += __shfl(incl, 63);
    }
    if (lane == 0) *total_out = carry;
}

__global__ void k_scan_blk(const int* __restrict__ deg, const int* __restrict__ boff,
                           int* __restrict__ rowptr, int n) {
    int tid = threadIdx.x;
    int lane = tid & 63, wave = tid >> 6;
    int i0 = blockIdx.x * 1024 + tid * 4;
    int v0 = 0, v1 = 0, v2 = 0, v3 = 0;
    if (i0 + 3 < n) {
        int4 v = *(const int4*)(deg + i0);
        v0 = v.x; v1 = v.y; v2 = v.z; v3 = v.w;
    } else {
        if (i0 + 0 < n) v0 = deg[i0 + 0];
        if (i0 + 1 < n) v1 = deg[i0 + 1];
        if (i0 + 2 < n) v2 = deg[i0 + 2];
        if (i0 + 3 < n) v3 = deg[i0 + 3];
    }
    int tot = v0 + v1 + v2 + v3;
    int incl = tot;
    #pragma unroll
    for (int off = 1; off < 64; off <<= 1) {
        int t = __shfl_up(incl, off);
        if (lane >= off) incl += t;
    }
    __shared__ int wsum[4];
    if (lane == 63) wsum[wave] = incl;
    __syncthreads();
    int wbase = 0;
    for (int w = 0; w < wave; ++w) wbase += wsum[w];
    int base = boff[blockIdx.x] + wbase + (incl - tot);
    if (i0 + 3 < n) {
        int4 r;
        r.x = base;
        r.y = base + v0;
        r.z = base + v0 + v1;
        r.w = base + v0 + v1 + v2;
        *(int4*)(rowptr + i0) = r;
    } else {
        if (i0 + 0 < n) rowptr[i0 + 0] = base;
        if (i0 + 1 < n) rowptr[i0 + 1] = base + v0;
        if (i0 + 2 < n) rowptr[i0 + 2] = base + v0 + v1;
        if (i0 + 3 < n) rowptr[i0 + 3] = base + v0 + v1 + v2;
    }
}

// ---------------- LDS-privatized bucket scatter (bucket = 512 dst nodes) ----------------

__global__ void k_binit(const int* __restrict__ rowptr, int* __restrict__ bcur, int NB) {
    int i = blockIdx.x * 256 + threadIdx.x;
    if (i < NB) bcur[i] = rowptr[i << BSH];
}

// 4096 edges per block: LDS histogram -> one global atomic per (block,bucket) -> ranked scatter
__global__ void k_bscatter(const int* __restrict__ src, const int* __restrict__ dst,
                           int* __restrict__ bcur, unsigned* __restrict__ ebuf,
                           int E, int NB) {
    extern __shared__ int lcur[];          // NB ints
    int tid = threadIdx.x;
    int e0 = blockIdx.x * 4096;
    for (int i = tid; i < NB; i += 256) lcur[i] = 0;
    __syncthreads();
    // phase 1: histogram
    #pragma unroll
    for (int i = 0; i < 4; ++i) {
        int e = e0 + i * 1024 + tid * 4;
        if (e + 3 < E) {
            int4 d = *(const int4*)(dst + e);
            atomicAdd(&lcur[d.x >> BSH], 1);
            atomicAdd(&lcur[d.y >> BSH], 1);
            atomicAdd(&lcur[d.z >> BSH], 1);
            atomicAdd(&lcur[d.w >> BSH], 1);
        } else {
            for (int j = 0; j < 4; ++j)
                if (e + j < E) atomicAdd(&lcur[dst[e + j] >> BSH], 1);
        }
    }
    __syncthreads();
    // phase 2: reserve global ranges
    for (int i = tid; i < NB; i += 256) {
        int c = lcur[i];
        lcur[i] = c ? atomicAdd(&bcur[i], c) : 0;
    }
    __syncthreads();
    // phase 3: ranked scatter
    #pragma unroll
    for (int i = 0; i < 4; ++i) {
        int e = e0 + i * 1024 + tid * 4;
        if (e + 3 < E) {
            int4 d = *(const int4*)(dst + e);
            int4 s = *(const int4*)(src + e);
            int p0 = atomicAdd(&lcur[d.x >> BSH], 1);
            ebuf[p0] = ((unsigned)s.x << BSH) | (unsigned)(d.x & (BSZ - 1));
            int p1 = atomicAdd(&lcur[d.y >> BSH], 1);
            ebuf[p1] = ((unsigned)s.y << BSH) | (unsigned)(d.y & (BSZ - 1));
            int p2 = atomicAdd(&lcur[d.z >> BSH], 1);
            ebuf[p2] = ((unsigned)s.z << BSH) | (unsigned)(d.z & (BSZ - 1));
            int p3 = atomicAdd(&lcur[d.w >> BSH], 1);
            ebuf[p3] = ((unsigned)s.w << BSH) | (unsigned)(d.w & (BSZ - 1));
        } else {
            for (int j = 0; j < 4; ++j) {
                if (e + j < E) {
                    int d = dst[e + j];
                    int p = atomicAdd(&lcur[d >> BSH], 1);
                    ebuf[p] = ((unsigned)src[e + j] << BSH) | (unsigned)(d & (BSZ - 1));
                }
            }
        }
    }
}

// one block per bucket: per-node cursors in LDS, localized col writes
__global__ void k_bfill(const unsigned* __restrict__ ebuf, const int* __restrict__ rowptr,
                        int* __restrict__ colarr, int N) {
    __shared__ int cur[BSZ];
    int b = blockIdx.x;
    int nbase = b << BSH;
    int ncnt = min(BSZ, N - nbase);
    int tid = threadIdx.x;
    for (int i = tid; i < ncnt; i += 256) cur[i] = rowptr[nbase + i];
    __syncthreads();
    int lo = rowptr[nbase];
    int hi = rowptr[nbase + ncnt];
    for (int j = lo + tid; j < hi; j += 256) {
        unsigned u = ebuf[j];
        int d = u & (BSZ - 1);
        int pos = atomicAdd(&cur[d], 1);
        colarr[pos] = (int)(u >> BSH);
    }
}

// ---------------- fused conv: agg (into LDS) + MFMA GEMM + BN + ReLU ----------------

__launch_bounds__(512)
__global__ void k_conv(const unsigned short* __restrict__ inb,
                       const int* __restrict__ rowptr, const int* __restrict__ col,
                       const unsigned short* __restrict__ Wt,
                       const float* __restrict__ bias, const float* __restrict__ gamma,
                       const float* __restrict__ beta, const float* __restrict__ mean,
                       const float* __restrict__ var,
                       unsigned short* __restrict__ outb, int N) {
    __shared__ unsigned short WL[128 * 128];   // 32 KB
    __shared__ unsigned short AL[64 * 128];    // 16 KB
    int tid = threadIdx.x;

    // stage Wt -> WL (swizzled: byte ^= (n&7)<<4)
    #pragma unroll
    for (int i = 0; i < 4; ++i) {
        int idx16 = i * 512 + tid;            // 16-byte chunk id, 2048 total
        int n = idx16 >> 4, k8 = idx16 & 15;
        unsigned ba = (unsigned)((n * 256 + k8 * 16) ^ ((n & 7) << 4));
        *(uint4*)((char*)WL + ba) = *(const uint4*)(Wt + n * 128 + k8 * 8);
    }

    // aggregate 64 rows into AL: 16 lanes per row, 16B chunk each, chunk c stored at c^row
    const uint4* in16 = (const uint4*)inb;
    int l = tid & 15;
    #pragma unroll
    for (int rep = 0; rep < 2; ++rep) {
        int rl = rep * 32 + (tid >> 4);
        int row = blockIdx.x * 64 + rl;
        uint4 o = make_uint4(0, 0, 0, 0);
        if (row < N) {
            float acc[8];
            uint4 v = in16[(long)row * 16 + l];
            acc[0] = bf_lo(v.x); acc[1] = bf_hi(v.x);
            acc[2] = bf_lo(v.y); acc[3] = bf_hi(v.y);
            acc[4] = bf_lo(v.z); acc[5] = bf_hi(v.z);
            acc[6] = bf_lo(v.w); acc[7] = bf_hi(v.w);
            int beg = rowptr[row], end = rowptr[row + 1];
            for (int j = beg; j < end; ++j) {
                int s = col[j];
                uint4 u = in16[(long)s * 16 + l];
                acc[0] += bf_lo(u.x); acc[1] += bf_hi(u.x);
                acc[2] += bf_lo(u.y); acc[3] += bf_hi(u.y);
                acc[4] += bf_lo(u.z); acc[5] += bf_hi(u.z);
                acc[6] += bf_lo(u.w); acc[7] += bf_hi(u.w);
            }
            o.x = (unsigned)f2bf(acc[0]) | ((unsigned)f2bf(acc[1]) << 16);
            o.y = (unsigned)f2bf(acc[2]) | ((unsigned)f2bf(acc[3]) << 16);
            o.z = (unsigned)f2bf(acc[4]) | ((unsigned)f2bf(acc[5]) << 16);
            o.w = (unsigned)f2bf(acc[6]) | ((unsigned)f2bf(acc[7]) << 16);
        }
        *(uint4*)((char*)AL + rl * 256 + ((l ^ (rl & 15)) << 4)) = o;
    }
    __syncthreads();

    int wid = tid >> 6, lane = tid & 63;
    int wr = wid & 3, wc = wid >> 2;
    int lr = lane & 15, lg = lane >> 4;
    f32x4 acc[4] = {};
    #pragma unroll
    for (int ks = 0; ks < 4; ++ks) {          // k0 = ks*32
        short8v a = *(const short8v*)((char*)AL + (wr * 16 + lr) * 256 + (((ks * 4 + lg) ^ lr) << 4));
        #pragma unroll
        for (int c = 0; c < 4; ++c) {
            int n = (wc * 4 + c) * 16 + lr;
            unsigned ba = (unsigned)((n * 256 + ks * 64 + lg * 16) ^ ((lr & 7) << 4));
            short8v b = *(const short8v*)((char*)WL + ba);
            acc[c] = __builtin_amdgcn_mfma_f32_16x16x32_bf16(a, b, acc[c], 0, 0, 0);
        }
    }

    // epilogue: lane holds D[wr*16 + lg*4 + r][(wc*4+c)*16 + lr]
    #pragma unroll
    for (int c = 0; c < 4; ++c) {
        int colc = (wc * 4 + c) * 16 + lr;
        float s = gamma[colc] * rsqrtf(var[colc] + 1e-5f);
        float sh = (bias[colc] - mean[colc]) * s + beta[colc];
        #pragma unroll
        for (int r = 0; r < 4; ++r) {
            int row = blockIdx.x * 64 + wr * 16 + lg * 4 + r;
            if (row < N) {
                float v = fmaxf(acc[c][r] * s + sh, 0.f);
                outb[(long)row * NCH + colc] = f2bf(v);
            }
        }
    }
}

// ---------------- global_add_pool (bf16 h, f32 pooled) ----------------

__global__ void k_pool(const unsigned short* __restrict__ h, const int* __restrict__ batch,
                       float* __restrict__ pooled, int sec, int N) {
    int start = blockIdx.x * 128;
    int c2 = threadIdx.x & 63;     // u32 col pair
    int rh = threadIdx.x >> 6;     // 0..3
    const unsigned* h32 = (const unsigned*)h;
    float a0 = 0.f, a1 = 0.f;
    int gcur = -1;
    for (int r = start + rh; r < start + 128; r += 4) {
        if (r >= N) break;
        int g = batch[r];
        if (g != gcur) {
            if (gcur >= 0) {
                atomicAdd(&pooled[gcur * 512 + sec * 128 + c2 * 2 + 0], a0);
                atomicAdd(&pooled[gcur * 512 + sec * 128 + c2 * 2 + 1], a1);
            }
            gcur = g;
            a0 = a1 = 0.f;
        }
        unsigned u = h32[(long)r * 64 + c2];
        a0 += bf_lo(u);
        a1 += bf_hi(u);
    }
    if (gcur >= 0) {
        atomicAdd(&pooled[gcur * 512 + sec * 128 + c2 * 2 + 0], a0);
        atomicAdd(&pooled[gcur * 512 + sec * 128 + c2 * 2 + 1], a1);
    }
}

// ---------------- MLP head + log_softmax ----------------

__launch_bounds__(256)
__global__ void k_mlp(const float* __restrict__ pooled,
                      const float* __restrict__ w1, const float* __restrict__ b1,
                      const float* __restrict__ w2, const float* __restrict__ b2,
                      float* __restrict__ out) {
    __shared__ float row[512];
    __shared__ float hid[256];
    __shared__ float o10[10];
    int g = blockIdx.x, tid = threadIdx.x;
    row[tid] = pooled[g * 512 + tid];
    row[tid + 256] = pooled[g * 512 + 256 + tid];
    __syncthreads();
    float acc = b1[tid];
    for (int k = 0; k < 512; ++k) acc += row[k] * w1[k * 256 + tid];
    hid[tid] = fmaxf(acc, 0.f);
    __syncthreads();
    if (tid < 10) {
        float o = b2[tid];
        for (int k = 0; k < 256; ++k) o += hid[k] * w2[k * 10 + tid];
        o10[tid] = o;
        out[g * 10 + tid] = o;
    }
    __syncthreads();
    if (tid == 0) {
        float m = o10[0];
        for (int j = 1; j < 10; ++j) m = fmaxf(m, o10[j]);
        float s = 0.f;
        for (int j = 0; j < 10; ++j) s += expf(o10[j] - m);
        float ls = m + logf(s);
        for (int j = 0; j < 10; ++j) out[NGRAPH * 10 + g * 10 + j] = o10[j] - ls;
    }
}

// ---------------- launch ----------------

extern "C" void kernel_launch(void* const* d_in, const int* in_sizes, int n_in,
                              void* d_out, int out_size, void* d_ws, size_t ws_size,
                              hipStream_t stream) {
    const float* x     = (const float*)d_in[0];
    const int*   eix   = (const int*)d_in[1];
    const int*   eiy   = (const int*)d_in[2];
    const int*   batch = (const int*)d_in[3];
    const float* convW = (const float*)d_in[4];
    const float* convB = (const float*)d_in[5];
    const float* gma   = (const float*)d_in[6];
    const float* bta   = (const float*)d_in[7];
    const float* mea   = (const float*)d_in[8];
    const float* var   = (const float*)d_in[9];
    const float* w1    = (const float*)d_in[10];
    const float* b1    = (const float*)d_in[11];
    const float* w2    = (const float*)d_in[12];
    const float* b2    = (const float*)d_in[13];
    float* out = (float*)d_out;

    int N = in_sizes[0] / NCH;
    int E = in_sizes[1] / 2;
    int NB = (N + BSZ - 1) >> BSH;   // dst buckets

    char* p = (char*)d_ws;
    auto alloc = [&](size_t bytes) {
        char* r = p;
        p += (bytes + 255) & ~(size_t)255;
        return r;
    };
    int* rowx     = (int*)alloc((size_t)(N + 1) * 4);
    int* rowy     = (int*)alloc((size_t)(N + 1) * 4);
    int* colx     = (int*)alloc((size_t)E * 4);
    int* coly     = (int*)alloc((size_t)E * 4);
    int* deg      = (int*)alloc((size_t)N * 4);
    int* bsum     = (int*)alloc(4096);
    int* bcur     = (int*)alloc((size_t)NB * 4);
    unsigned* ebuf = (unsigned*)alloc((size_t)E * 4);
    unsigned short* xb   = (unsigned short*)alloc((size_t)N * NCH * 2);
    unsigned short* Wt   = (unsigned short*)alloc((size_t)4 * NCH * NCH * 2);
    unsigned short* bufA = (unsigned short*)alloc((size_t)N * NCH * 2);
    unsigned short* bufB = (unsigned short*)alloc((size_t)N * NCH * 2);
    float* pooled = (float*)alloc((size_t)NGRAPH * 512 * 4);

    const int* srcx = eix;
    const int* dstx = eix + E;
    const int* srcy = eiy;
    const int* dsty = eiy + E;

    int EB = (E + 255) / 256;
    int SB = (E + 4095) / 4096;      // bscatter blocks
    int GB = (N + 63) / 64;          // conv blocks
    int PB = (N + 127) / 128;        // pool blocks
    int NBS = (N + 1023) / 1024;     // scan blocks
    int BIB = (NB + 255) / 256;
    size_t lds_sc = (size_t)NB * 4;

    // dtype prep
    k_cvt<<<2048, 256, 0, stream>>>(x, xb, (long)N * 32);
    k_prepw<<<256, 256, 0, stream>>>(convW, Wt);

    // ---- CSR x ----
    hipMemsetAsync(deg, 0, (size_t)N * 4, stream);
    k_deg<<<EB, 256, 0, stream>>>(dstx, deg, E);
    k_bsum<<<NBS, 256, 0, stream>>>(deg, bsum, N);
    k_scan_sums<<<1, 64, 0, stream>>>(bsum, NBS, rowx + N);
    k_scan_blk<<<NBS, 256, 0, stream>>>(deg, bsum, rowx, N);
    k_binit<<<BIB, 256, 0, stream>>>(rowx, bcur, NB);
    k_bscatter<<<SB, 256, lds_sc, stream>>>(srcx, dstx, bcur, ebuf, E, NB);
    k_bfill<<<NB, 256, 0, stream>>>(ebuf, rowx, colx, N);
    // ---- CSR y ----
    hipMemsetAsync(deg, 0, (size_t)N * 4, stream);
    k_deg<<<EB, 256, 0, stream>>>(dsty, deg, E);
    k_bsum<<<NBS, 256, 0, stream>>>(deg, bsum, N);
    k_scan_sums<<<1, 64, 0, stream>>>(bsum, NBS, rowy + N);
    k_scan_blk<<<NBS, 256, 0, stream>>>(deg, bsum, rowy, N);
    k_binit<<<BIB, 256, 0, stream>>>(rowy, bcur, NB);
    k_bscatter<<<SB, 256, lds_sc, stream>>>(srcy, dsty, bcur, ebuf, E, NB);
    k_bfill<<<NB, 256, 0, stream>>>(ebuf, rowy, coly, N);

    hipMemsetAsync(pooled, 0, (size_t)NGRAPH * 512 * 4, stream);

    // conv1_x: xb -> bufA
    k_conv<<<GB, 512, 0, stream>>>(xb, rowx, colx, Wt + 0 * NCH * NCH, convB + 0 * NCH,
                                   gma + 0 * NCH, bta + 0 * NCH, mea + 0 * NCH, var + 0 * NCH,
                                   bufA, N);
    k_pool<<<PB, 256, 0, stream>>>(bufA, batch, pooled, 0, N);

    // conv2_x: bufA -> bufB
    k_conv<<<GB, 512, 0, stream>>>(bufA, rowx, colx, Wt + 1 * NCH * NCH, convB + 1 * NCH,
                                   gma + 1 * NCH, bta + 1 * NCH, mea + 1 * NCH, var + 1 * NCH,
                                   bufB, N);
    k_pool<<<PB, 256, 0, stream>>>(bufB, batch, pooled, 1, N);

    // conv1_y: xb -> bufA
    k_conv<<<GB, 512, 0, stream>>>(xb, rowy, coly, Wt + 2 * NCH * NCH, convB + 2 * NCH,
                                   gma + 2 * NCH, bta + 2 * NCH, mea + 2 * NCH, var + 2 * NCH,
                                   bufA, N);
    k_pool<<<PB, 256, 0, stream>>>(bufA, batch, pooled, 2, N);

    // conv2_y: bufA -> bufB
    k_conv<<<GB, 512, 0, stream>>>(bufA, rowy, coly, Wt + 3 * NCH * NCH, convB + 3 * NCH,
                                   gma + 3 * NCH, bta + 3 * NCH, mea + 3 * NCH, var + 3 * NCH,
                                   bufB, N);
    k_pool<<<PB, 256, 0, stream>>>(bufB, batch, pooled, 3, N);

    // head
    k_mlp<<<NGRAPH, 256, 0, stream>>>(pooled, w1, b1, w2, b2, out);
}

// Round 6
// 708.520 us; speedup vs baseline: 2.0651x; 1.0709x over previous
//
#include <hip/hip_runtime.h>
#include <math.h>

#define NCH 128
#define NGRAPH 128
#define BSH 9                 // bucket shift: 512 nodes per bucket
#define BSZ (1 << BSH)

typedef __attribute__((ext_vector_type(8))) short short8v;
typedef __attribute__((ext_vector_type(4))) float f32x4;

static __device__ __forceinline__ float bf_lo(unsigned u) { return __uint_as_float(u << 16); }
static __device__ __forceinline__ float bf_hi(unsigned u) { return __uint_as_float(u & 0xffff0000u); }
static __device__ __forceinline__ unsigned short f2bf(float f) {
    unsigned u = __float_as_uint(f);
    return (unsigned short)((u + 0x7fffu + ((u >> 16) & 1u)) >> 16);
}

// ---------------- dtype prep ----------------

__global__ void k_cvt(const float* __restrict__ in, unsigned short* __restrict__ outb, long n4) {
    long i = (long)blockIdx.x * 256 + threadIdx.x;
    long stride = (long)gridDim.x * 256;
    for (; i < n4; i += stride) {
        float4 v = *(const float4*)(in + i * 4);
        ushort4 o;
        o.x = f2bf(v.x); o.y = f2bf(v.y); o.z = f2bf(v.z); o.w = f2bf(v.w);
        *(ushort4*)(outb + i * 4) = o;
    }
}

// convW[i][k][n] f32 -> Wt[i][n][k] bf16 (transposed)
__global__ void k_prepw(const float* __restrict__ W, unsigned short* __restrict__ Wt) {
    int idx = blockIdx.x * 256 + threadIdx.x;   // 65536 total
    int i = idx >> 14, rem = idx & 16383;
    int n = rem >> 7, k = rem & 127;
    Wt[idx] = f2bf(W[i * 16384 + k * 128 + n]);
}

// ---------------- CSR build ----------------

__global__ void k_deg(const int* __restrict__ dst, int* __restrict__ deg, int E) {
    int e = blockIdx.x * 256 + threadIdx.x;
    if (e < E) atomicAdd(&deg[dst[e]], 1);
}

__global__ void k_bsum(const int* __restrict__ deg, int* __restrict__ bsum, int n) {
    int tid = threadIdx.x;
    int i0 = blockIdx.x * 1024 + tid * 4;
    int s = 0;
    if (i0 + 3 < n) {
        int4 v = *(const int4*)(deg + i0);
        s = v.x + v.y + v.z + v.w;
    } else {
        for (int j = 0; j < 4; ++j) if (i0 + j < n) s += deg[i0 + j];
    }
    #pragma unroll
    for (int off = 32; off; off >>= 1) s += __shfl_down(s, off);
    __shared__ int ws[4];
    if ((tid & 63) == 0) ws[tid >> 6] = s;
    __syncthreads();
    if (tid == 0) bsum[blockIdx.x] = ws[0] + ws[1] + ws[2] + ws[3];
}

__global__ void k_scan_sums(int* __restrict__ bsum, int nb, int* __restrict__ total_out) {
    int lane = threadIdx.x;
    int carry = 0;
    for (int base = 0; base < nb; base += 64) {
        int v = (base + lane < nb) ? bsum[base + lane] : 0;
        int incl = v;
        #pragma unroll
        for (int off = 1; off < 64; off <<= 1) {
            int t = __shfl_up(incl, off);
            if (lane >= off) incl += t;
        }
        if (base + lane < nb) bsum[base + lane] = carry + incl - v;
        carry += __shfl(incl, 63);
    }
    if (lane == 0) *total_out = carry;
}

__global__ void k_scan_blk(const int* __restrict__ deg, const int* __restrict__ boff,
                           int* __restrict__ rowptr, int n) {
    int tid = threadIdx.x;
    int lane = tid & 63, wave = tid >> 6;
    int i0 = blockIdx.x * 1024 + tid * 4;
    int v0 = 0, v1 = 0, v2 = 0, v3 = 0;
    if (i0 + 3 < n) {
        int4 v = *(const int4*)(deg + i0);
        v0 = v.x; v1 = v.y; v2 = v.z; v3 = v.w;
    } else {
        if (i0 + 0 < n) v0 = deg[i0 + 0];
        if (i0 + 1 < n) v1 = deg[i0 + 1];
        if (i0 + 2 < n) v2 = deg[i0 + 2];
        if (i0 + 3 < n) v3 = deg[i0 + 3];
    }
    int tot = v0 + v1 + v2 + v3;
    int incl = tot;
    #pragma unroll
    for (int off = 1; off < 64; off <<= 1) {
        int t = __shfl_up(incl, off);
        if (lane >= off) incl += t;
    }
    __shared__ int wsum[4];
    if (lane == 63) wsum[wave] = incl;
    __syncthreads();
    int wbase = 0;
    for (int w = 0; w < wave; ++w) wbase += wsum[w];
    int base = boff[blockIdx.x] + wbase + (incl - tot);
    if (i0 + 3 < n) {
        int4 r;
        r.x = base;
        r.y = base + v0;
        r.z = base + v0 + v1;
        r.w = base + v0 + v1 + v2;
        *(int4*)(rowptr + i0) = r;
    } else {
        if (i0 + 0 < n) rowptr[i0 + 0] = base;
        if (i0 + 1 < n) rowptr[i0 + 1] = base + v0;
        if (i0 + 2 < n) rowptr[i0 + 2] = base + v0 + v1;
        if (i0 + 3 < n) rowptr[i0 + 3] = base + v0 + v1 + v2;
    }
}

// ---------------- LDS-privatized bucket scatter (bucket = 512 dst nodes) ----------------

__global__ void k_binit(const int* __restrict__ rowptr, int* __restrict__ bcur, int NB) {
    int i = blockIdx.x * 256 + threadIdx.x;
    if (i < NB) bcur[i] = rowptr[i << BSH];
}

__global__ void k_bscatter(const int* __restrict__ src, const int* __restrict__ dst,
                           int* __restrict__ bcur, unsigned* __restrict__ ebuf,
                           int E, int NB) {
    extern __shared__ int lcur[];          // NB ints
    int tid = threadIdx.x;
    int e0 = blockIdx.x * 4096;
    for (int i = tid; i < NB; i += 256) lcur[i] = 0;
    __syncthreads();
    #pragma unroll
    for (int i = 0; i < 4; ++i) {
        int e = e0 + i * 1024 + tid * 4;
        if (e + 3 < E) {
            int4 d = *(const int4*)(dst + e);
            atomicAdd(&lcur[d.x >> BSH], 1);
            atomicAdd(&lcur[d.y >> BSH], 1);
            atomicAdd(&lcur[d.z >> BSH], 1);
            atomicAdd(&lcur[d.w >> BSH], 1);
        } else {
            for (int j = 0; j < 4; ++j)
                if (e + j < E) atomicAdd(&lcur[dst[e + j] >> BSH], 1);
        }
    }
    __syncthreads();
    for (int i = tid; i < NB; i += 256) {
        int c = lcur[i];
        lcur[i] = c ? atomicAdd(&bcur[i], c) : 0;
    }
    __syncthreads();
    #pragma unroll
    for (int i = 0; i < 4; ++i) {
        int e = e0 + i * 1024 + tid * 4;
        if (e + 3 < E) {
            int4 d = *(const int4*)(dst + e);
            int4 s = *(const int4*)(src + e);
            int p0 = atomicAdd(&lcur[d.x >> BSH], 1);
            ebuf[p0] = ((unsigned)s.x << BSH) | (unsigned)(d.x & (BSZ - 1));
            int p1 = atomicAdd(&lcur[d.y >> BSH], 1);
            ebuf[p1] = ((unsigned)s.y << BSH) | (unsigned)(d.y & (BSZ - 1));
            int p2 = atomicAdd(&lcur[d.z >> BSH], 1);
            ebuf[p2] = ((unsigned)s.z << BSH) | (unsigned)(d.z & (BSZ - 1));
            int p3 = atomicAdd(&lcur[d.w >> BSH], 1);
            ebuf[p3] = ((unsigned)s.w << BSH) | (unsigned)(d.w & (BSZ - 1));
        } else {
            for (int j = 0; j < 4; ++j) {
                if (e + j < E) {
                    int d = dst[e + j];
                    int p = atomicAdd(&lcur[d >> BSH], 1);
                    ebuf[p] = ((unsigned)src[e + j] << BSH) | (unsigned)(d & (BSZ - 1));
                }
            }
        }
    }
}

__global__ void k_bfill(const unsigned* __restrict__ ebuf, const int* __restrict__ rowptr,
                        int* __restrict__ colarr, int N) {
    __shared__ int cur[BSZ];
    int b = blockIdx.x;
    int nbase = b << BSH;
    int ncnt = min(BSZ, N - nbase);
    int tid = threadIdx.x;
    for (int i = tid; i < ncnt; i += 256) cur[i] = rowptr[nbase + i];
    __syncthreads();
    int lo = rowptr[nbase];
    int hi = rowptr[nbase + ncnt];
    for (int j = lo + tid; j < hi; j += 256) {
        unsigned u = ebuf[j];
        int d = u & (BSZ - 1);
        int pos = atomicAdd(&cur[d], 1);
        colarr[pos] = (int)(u >> BSH);
    }
}

// ---------------- fused conv: agg (4-deep unrolled gather -> LDS) + MFMA + BN + ReLU ----------------
// 512 threads = 8 waves; tile 64 rows x 128 cols. LDS = A-tile only (16 KB).
// W (32 KB) is read directly from global per MFMA step: L1/L2-resident, coalesced 64B groups.

__launch_bounds__(512)
__global__ void k_conv(const unsigned short* __restrict__ inb,
                       const int* __restrict__ rowptr, const int* __restrict__ col,
                       const unsigned short* __restrict__ Wt,
                       const float* __restrict__ bias, const float* __restrict__ gamma,
                       const float* __restrict__ beta, const float* __restrict__ mean,
                       const float* __restrict__ var,
                       unsigned short* __restrict__ outb, int N) {
    __shared__ unsigned short AL[64 * 128];    // 16 KB
    int tid = threadIdx.x;

    const uint4* in16 = (const uint4*)inb;
    int l = tid & 15;
    #pragma unroll
    for (int rep = 0; rep < 2; ++rep) {
        int rl = rep * 32 + (tid >> 4);
        int row = blockIdx.x * 64 + rl;
        uint4 o = make_uint4(0, 0, 0, 0);
        if (row < N) {
            float acc[8];
            uint4 v = in16[(long)row * 16 + l];
            acc[0] = bf_lo(v.x); acc[1] = bf_hi(v.x);
            acc[2] = bf_lo(v.y); acc[3] = bf_hi(v.y);
            acc[4] = bf_lo(v.z); acc[5] = bf_hi(v.z);
            acc[6] = bf_lo(v.w); acc[7] = bf_hi(v.w);
            int beg = rowptr[row], end = rowptr[row + 1];
            int j = beg;
            // 4-deep software pipeline: 4 independent gathers in flight
            for (; j + 4 <= end; j += 4) {
                int s0 = col[j + 0], s1 = col[j + 1], s2 = col[j + 2], s3 = col[j + 3];
                uint4 u0 = in16[(long)s0 * 16 + l];
                uint4 u1 = in16[(long)s1 * 16 + l];
                uint4 u2 = in16[(long)s2 * 16 + l];
                uint4 u3 = in16[(long)s3 * 16 + l];
                acc[0] += bf_lo(u0.x); acc[1] += bf_hi(u0.x);
                acc[2] += bf_lo(u0.y); acc[3] += bf_hi(u0.y);
                acc[4] += bf_lo(u0.z); acc[5] += bf_hi(u0.z);
                acc[6] += bf_lo(u0.w); acc[7] += bf_hi(u0.w);
                acc[0] += bf_lo(u1.x); acc[1] += bf_hi(u1.x);
                acc[2] += bf_lo(u1.y); acc[3] += bf_hi(u1.y);
                acc[4] += bf_lo(u1.z); acc[5] += bf_hi(u1.z);
                acc[6] += bf_lo(u1.w); acc[7] += bf_hi(u1.w);
                acc[0] += bf_lo(u2.x); acc[1] += bf_hi(u2.x);
                acc[2] += bf_lo(u2.y); acc[3] += bf_hi(u2.y);
                acc[4] += bf_lo(u2.z); acc[5] += bf_hi(u2.z);
                acc[6] += bf_lo(u2.w); acc[7] += bf_hi(u2.w);
                acc[0] += bf_lo(u3.x); acc[1] += bf_hi(u3.x);
                acc[2] += bf_lo(u3.y); acc[3] += bf_hi(u3.y);
                acc[4] += bf_lo(u3.z); acc[5] += bf_hi(u3.z);
                acc[6] += bf_lo(u3.w); acc[7] += bf_hi(u3.w);
            }
            for (; j < end; ++j) {
                int s = col[j];
                uint4 u = in16[(long)s * 16 + l];
                acc[0] += bf_lo(u.x); acc[1] += bf_hi(u.x);
                acc[2] += bf_lo(u.y); acc[3] += bf_hi(u.y);
                acc[4] += bf_lo(u.z); acc[5] += bf_hi(u.z);
                acc[6] += bf_lo(u.w); acc[7] += bf_hi(u.w);
            }
            o.x = (unsigned)f2bf(acc[0]) | ((unsigned)f2bf(acc[1]) << 16);
            o.y = (unsigned)f2bf(acc[2]) | ((unsigned)f2bf(acc[3]) << 16);
            o.z = (unsigned)f2bf(acc[4]) | ((unsigned)f2bf(acc[5]) << 16);
            o.w = (unsigned)f2bf(acc[6]) | ((unsigned)f2bf(acc[7]) << 16);
        }
        *(uint4*)((char*)AL + rl * 256 + ((l ^ (rl & 15)) << 4)) = o;
    }
    __syncthreads();

    int wid = tid >> 6, lane = tid & 63;
    int wr = wid & 3, wc = wid >> 2;
    int lr = lane & 15, lg = lane >> 4;
    f32x4 acc[4] = {};
    #pragma unroll
    for (int ks = 0; ks < 4; ++ks) {          // k0 = ks*32
        short8v a = *(const short8v*)((char*)AL + (wr * 16 + lr) * 256 + (((ks * 4 + lg) ^ lr) << 4));
        #pragma unroll
        for (int c = 0; c < 4; ++c) {
            int n = (wc * 4 + c) * 16 + lr;
            short8v b = *(const short8v*)(Wt + n * 128 + ks * 32 + lg * 8);
            acc[c] = __builtin_amdgcn_mfma_f32_16x16x32_bf16(a, b, acc[c], 0, 0, 0);
        }
    }

    // epilogue: lane holds D[wr*16 + lg*4 + r][(wc*4+c)*16 + lr]
    #pragma unroll
    for (int c = 0; c < 4; ++c) {
        int colc = (wc * 4 + c) * 16 + lr;
        float s = gamma[colc] * rsqrtf(var[colc] + 1e-5f);
        float sh = (bias[colc] - mean[colc]) * s + beta[colc];
        #pragma unroll
        for (int r = 0; r < 4; ++r) {
            int row = blockIdx.x * 64 + wr * 16 + lg * 4 + r;
            if (row < N) {
                float v = fmaxf(acc[c][r] * s + sh, 0.f);
                outb[(long)row * NCH + colc] = f2bf(v);
            }
        }
    }
}

// ---------------- global_add_pool (bf16 h, f32 pooled) ----------------

__global__ void k_pool(const unsigned short* __restrict__ h, const int* __restrict__ batch,
                       float* __restrict__ pooled, int sec, int N) {
    int start = blockIdx.x * 128;
    int c2 = threadIdx.x & 63;     // u32 col pair
    int rh = threadIdx.x >> 6;     // 0..3
    const unsigned* h32 = (const unsigned*)h;
    float a0 = 0.f, a1 = 0.f;
    int gcur = -1;
    for (int r = start + rh; r < start + 128; r += 4) {
        if (r >= N) break;
        int g = batch[r];
        if (g != gcur) {
            if (gcur >= 0) {
                atomicAdd(&pooled[gcur * 512 + sec * 128 + c2 * 2 + 0], a0);
                atomicAdd(&pooled[gcur * 512 + sec * 128 + c2 * 2 + 1], a1);
            }
            gcur = g;
            a0 = a1 = 0.f;
        }
        unsigned u = h32[(long)r * 64 + c2];
        a0 += bf_lo(u);
        a1 += bf_hi(u);
    }
    if (gcur >= 0) {
        atomicAdd(&pooled[gcur * 512 + sec * 128 + c2 * 2 + 0], a0);
        atomicAdd(&pooled[gcur * 512 + sec * 128 + c2 * 2 + 1], a1);
    }
}

// ---------------- MLP head + log_softmax ----------------

__launch_bounds__(256)
__global__ void k_mlp(const float* __restrict__ pooled,
                      const float* __restrict__ w1, const float* __restrict__ b1,
                      const float* __restrict__ w2, const float* __restrict__ b2,
                      float* __restrict__ out) {
    __shared__ float row[512];
    __shared__ float hid[256];
    __shared__ float o10[10];
    int g = blockIdx.x, tid = threadIdx.x;
    row[tid] = pooled[g * 512 + tid];
    row[tid + 256] = pooled[g * 512 + 256 + tid];
    __syncthreads();
    float acc = b1[tid];
    for (int k = 0; k < 512; ++k) acc += row[k] * w1[k * 256 + tid];
    hid[tid] = fmaxf(acc, 0.f);
    __syncthreads();
    if (tid < 10) {
        float o = b2[tid];
        for (int k = 0; k < 256; ++k) o += hid[k] * w2[k * 10 + tid];
        o10[tid] = o;
        out[g * 10 + tid] = o;
    }
    __syncthreads();
    if (tid == 0) {
        float m = o10[0];
        for (int j = 1; j < 10; ++j) m = fmaxf(m, o10[j]);
        float s = 0.f;
        for (int j = 0; j < 10; ++j) s += expf(o10[j] - m);
        float ls = m + logf(s);
        for (int j = 0; j < 10; ++j) out[NGRAPH * 10 + g * 10 + j] = o10[j] - ls;
    }
}

// ---------------- launch ----------------

extern "C" void kernel_launch(void* const* d_in, const int* in_sizes, int n_in,
                              void* d_out, int out_size, void* d_ws, size_t ws_size,
                              hipStream_t stream) {
    const float* x     = (const float*)d_in[0];
    const int*   eix   = (const int*)d_in[1];
    const int*   eiy   = (const int*)d_in[2];
    const int*   batch = (const int*)d_in[3];
    const float* convW = (const float*)d_in[4];
    const float* convB = (const float*)d_in[5];
    const float* gma   = (const float*)d_in[6];
    const float* bta   = (const float*)d_in[7];
    const float* mea   = (const float*)d_in[8];
    const float* var   = (const float*)d_in[9];
    const float* w1    = (const float*)d_in[10];
    const float* b1    = (const float*)d_in[11];
    const float* w2    = (const float*)d_in[12];
    const float* b2    = (const float*)d_in[13];
    float* out = (float*)d_out;

    int N = in_sizes[0] / NCH;
    int E = in_sizes[1] / 2;
    int NB = (N + BSZ - 1) >> BSH;   // dst buckets

    char* p = (char*)d_ws;
    auto alloc = [&](size_t bytes) {
        char* r = p;
        p += (bytes + 255) & ~(size_t)255;
        return r;
    };
    int* rowx     = (int*)alloc((size_t)(N + 1) * 4);
    int* rowy     = (int*)alloc((size_t)(N + 1) * 4);
    int* colx     = (int*)alloc((size_t)E * 4);
    int* coly     = (int*)alloc((size_t)E * 4);
    int* deg      = (int*)alloc((size_t)N * 4);
    int* bsum     = (int*)alloc(4096);
    int* bcur     = (int*)alloc((size_t)NB * 4);
    unsigned* ebuf = (unsigned*)alloc((size_t)E * 4);
    unsigned short* xb   = (unsigned short*)alloc((size_t)N * NCH * 2);
    unsigned short* Wt   = (unsigned short*)alloc((size_t)4 * NCH * NCH * 2);
    unsigned short* bufA = (unsigned short*)alloc((size_t)N * NCH * 2);
    unsigned short* bufB = (unsigned short*)alloc((size_t)N * NCH * 2);
    float* pooled = (float*)alloc((size_t)NGRAPH * 512 * 4);

    const int* srcx = eix;
    const int* dstx = eix + E;
    const int* srcy = eiy;
    const int* dsty = eiy + E;

    int EB = (E + 255) / 256;
    int SB = (E + 4095) / 4096;      // bscatter blocks
    int GB = (N + 63) / 64;          // conv blocks
    int PB = (N + 127) / 128;        // pool blocks
    int NBS = (N + 1023) / 1024;     // scan blocks
    int BIB = (NB + 255) / 256;
    size_t lds_sc = (size_t)NB * 4;

    // dtype prep
    k_cvt<<<2048, 256, 0, stream>>>(x, xb, (long)N * 32);
    k_prepw<<<256, 256, 0, stream>>>(convW, Wt);

    // ---- CSR x ----
    hipMemsetAsync(deg, 0, (size_t)N * 4, stream);
    k_deg<<<EB, 256, 0, stream>>>(dstx, deg, E);
    k_bsum<<<NBS, 256, 0, stream>>>(deg, bsum, N);
    k_scan_sums<<<1, 64, 0, stream>>>(bsum, NBS, rowx + N);
    k_scan_blk<<<NBS, 256, 0, stream>>>(deg, bsum, rowx, N);
    k_binit<<<BIB, 256, 0, stream>>>(rowx, bcur, NB);
    k_bscatter<<<SB, 256, lds_sc, stream>>>(srcx, dstx, bcur, ebuf, E, NB);
    k_bfill<<<NB, 256, 0, stream>>>(ebuf, rowx, colx, N);
    // ---- CSR y ----
    hipMemsetAsync(deg, 0, (size_t)N * 4, stream);
    k_deg<<<EB, 256, 0, stream>>>(dsty, deg, E);
    k_bsum<<<NBS, 256, 0, stream>>>(deg, bsum, N);
    k_scan_sums<<<1, 64, 0, stream>>>(bsum, NBS, rowy + N);
    k_scan_blk<<<NBS, 256, 0, stream>>>(deg, bsum, rowy, N);
    k_binit<<<BIB, 256, 0, stream>>>(rowy, bcur, NB);
    k_bscatter<<<SB, 256, lds_sc, stream>>>(srcy, dsty, bcur, ebuf, E, NB);
    k_bfill<<<NB, 256, 0, stream>>>(ebuf, rowy, coly, N);

    hipMemsetAsync(pooled, 0, (size_t)NGRAPH * 512 * 4, stream);

    // conv1_x: xb -> bufA
    k_conv<<<GB, 512, 0, stream>>>(xb, rowx, colx, Wt + 0 * NCH * NCH, convB + 0 * NCH,
                                   gma + 0 * NCH, bta + 0 * NCH, mea + 0 * NCH, var + 0 * NCH,
                                   bufA, N);
    k_pool<<<PB, 256, 0, stream>>>(bufA, batch, pooled, 0, N);

    // conv2_x: bufA -> bufB
    k_conv<<<GB, 512, 0, stream>>>(bufA, rowx, colx, Wt + 1 * NCH * NCH, convB + 1 * NCH,
                                   gma + 1 * NCH, bta + 1 * NCH, mea + 1 * NCH, var + 1 * NCH,
                                   bufB, N);
    k_pool<<<PB, 256, 0, stream>>>(bufB, batch, pooled, 1, N);

    // conv1_y: xb -> bufA
    k_conv<<<GB, 512, 0, stream>>>(xb, rowy, coly, Wt + 2 * NCH * NCH, convB + 2 * NCH,
                                   gma + 2 * NCH, bta + 2 * NCH, mea + 2 * NCH, var + 2 * NCH,
                                   bufA, N);
    k_pool<<<PB, 256, 0, stream>>>(bufA, batch, pooled, 2, N);

    // conv2_y: bufA -> bufB
    k_conv<<<GB, 512, 0, stream>>>(bufA, rowy, coly, Wt + 3 * NCH * NCH, convB + 3 * NCH,
                                   gma + 3 * NCH, bta + 3 * NCH, mea + 3 * NCH, var + 3 * NCH,
                                   bufB, N);
    k_pool<<<PB, 256, 0, stream>>>(bufB, batch, pooled, 3, N);

    // head
    k_mlp<<<NGRAPH, 256, 0, stream>>>(pooled, w1, b1, w2, b2, out);
}

// Round 7
// 632.739 us; speedup vs baseline: 2.3124x; 1.1198x over previous
//
#include <hip/hip_runtime.h>
#include <math.h>

#define NCH 128
#define NGRAPH 128
#define BSH 9                 // bucket shift: 512 nodes per bucket
#define BSZ (1 << BSH)

typedef __attribute__((ext_vector_type(8))) short short8v;
typedef __attribute__((ext_vector_type(4))) float f32x4;

static __device__ __forceinline__ float bf_lo(unsigned u) { return __uint_as_float(u << 16); }
static __device__ __forceinline__ float bf_hi(unsigned u) { return __uint_as_float(u & 0xffff0000u); }
static __device__ __forceinline__ unsigned short f2bf(float f) {
    unsigned u = __float_as_uint(f);
    return (unsigned short)((u + 0x7fffu + ((u >> 16) & 1u)) >> 16);
}

// ---------------- prep: blocks [0,256) transpose W -> bf16; rest convert x -> bf16 ----------------

__global__ void k_prep(const float* __restrict__ W, unsigned short* __restrict__ Wt,
                       const float* __restrict__ x, unsigned short* __restrict__ xb, long n4) {
    int b = blockIdx.x;
    if (b < 256) {
        int idx = b * 256 + threadIdx.x;   // 65536 = 4*128*128
        int i = idx >> 14, rem = idx & 16383;
        int n = rem >> 7, k = rem & 127;
        Wt[idx] = f2bf(W[i * 16384 + k * 128 + n]);
    } else {
        long i = (long)(b - 256) * 256 + threadIdx.x;
        long stride = 2048L * 256;
        for (; i < n4; i += stride) {
            float4 v = *(const float4*)(x + i * 4);
            ushort4 o;
            o.x = f2bf(v.x); o.y = f2bf(v.y); o.z = f2bf(v.z); o.w = f2bf(v.w);
            *(ushort4*)(xb + i * 4) = o;
        }
    }
}

// ---------------- bucket histogram (both edge sets; LDS-privatized) ----------------

__global__ void k_bhist(const int* __restrict__ dstx, const int* __restrict__ dsty,
                        int* __restrict__ bghist, int E, int SB, int NB) {
    extern __shared__ int lh[];            // NB ints
    int b = blockIdx.x;
    int h = b >= SB;
    const int* dst = h ? dsty : dstx;
    int* gh = bghist + h * NB;
    int b2 = b - h * SB;
    int tid = threadIdx.x;
    for (int i = tid; i < NB; i += 256) lh[i] = 0;
    __syncthreads();
    int e0 = b2 * 4096;
    #pragma unroll
    for (int i = 0; i < 4; ++i) {
        int e = e0 + i * 1024 + tid * 4;
        if (e + 3 < E) {
            int4 d = *(const int4*)(dst + e);
            atomicAdd(&lh[d.x >> BSH], 1);
            atomicAdd(&lh[d.y >> BSH], 1);
            atomicAdd(&lh[d.z >> BSH], 1);
            atomicAdd(&lh[d.w >> BSH], 1);
        } else {
            for (int j = 0; j < 4; ++j)
                if (e + j < E) atomicAdd(&lh[dst[e + j] >> BSH], 1);
        }
    }
    __syncthreads();
    for (int i = tid; i < NB; i += 256) {
        int c = lh[i];
        if (c) atomicAdd(&gh[i], c);
    }
}

// ---------------- scan bucket counts -> boff (preserved) and bcur (working) ----------------
// 1 block, 128 threads: wave0 = x set, wave1 = y set.

__global__ void k_bhscan(const int* __restrict__ bghist, int* __restrict__ boff,
                         int* __restrict__ bcur, int NB) {
    int w = threadIdx.x >> 6, lane = threadIdx.x & 63;
    if (w < 2) {
        const int* hh = bghist + w * NB;
        int* bo = boff + w * NB;
        int* bc = bcur + w * NB;
        int carry = 0;
        for (int base = 0; base < NB; base += 64) {
            int v = (base + lane < NB) ? hh[base + lane] : 0;
            int incl = v;
            #pragma unroll
            for (int off = 1; off < 64; off <<= 1) {
                int t = __shfl_up(incl, off);
                if (lane >= off) incl += t;
            }
            if (base + lane < NB) {
                int ex = carry + incl - v;
                bo[base + lane] = ex;
                bc[base + lane] = ex;
            }
            carry += __shfl(incl, 63);
        }
    }
}

// ---------------- ranked bucket scatter (both sets; LDS-privatized) ----------------

__global__ void k_bscatter(const int* __restrict__ srcx, const int* __restrict__ dstx,
                           const int* __restrict__ srcy, const int* __restrict__ dsty,
                           int* __restrict__ bcur, unsigned* __restrict__ ebufx,
                           unsigned* __restrict__ ebufy, int E, int SB, int NB) {
    extern __shared__ int lcur[];          // NB ints
    int b = blockIdx.x;
    int h = b >= SB;
    int b2 = b - h * SB;
    const int* src = h ? srcy : srcx;
    const int* dst = h ? dsty : dstx;
    int* bc = bcur + h * NB;
    unsigned* ebuf = h ? ebufy : ebufx;
    int tid = threadIdx.x;
    int e0 = b2 * 4096;
    for (int i = tid; i < NB; i += 256) lcur[i] = 0;
    __syncthreads();
    #pragma unroll
    for (int i = 0; i < 4; ++i) {
        int e = e0 + i * 1024 + tid * 4;
        if (e + 3 < E) {
            int4 d = *(const int4*)(dst + e);
            atomicAdd(&lcur[d.x >> BSH], 1);
            atomicAdd(&lcur[d.y >> BSH], 1);
            atomicAdd(&lcur[d.z >> BSH], 1);
            atomicAdd(&lcur[d.w >> BSH], 1);
        } else {
            for (int j = 0; j < 4; ++j)
                if (e + j < E) atomicAdd(&lcur[dst[e + j] >> BSH], 1);
        }
    }
    __syncthreads();
    for (int i = tid; i < NB; i += 256) {
        int c = lcur[i];
        lcur[i] = c ? atomicAdd(&bc[i], c) : 0;
    }
    __syncthreads();
    #pragma unroll
    for (int i = 0; i < 4; ++i) {
        int e = e0 + i * 1024 + tid * 4;
        if (e + 3 < E) {
            int4 d = *(const int4*)(dst + e);
            int4 s = *(const int4*)(src + e);
            int p0 = atomicAdd(&lcur[d.x >> BSH], 1);
            ebuf[p0] = ((unsigned)s.x << BSH) | (unsigned)(d.x & (BSZ - 1));
            int p1 = atomicAdd(&lcur[d.y >> BSH], 1);
            ebuf[p1] = ((unsigned)s.y << BSH) | (unsigned)(d.y & (BSZ - 1));
            int p2 = atomicAdd(&lcur[d.z >> BSH], 1);
            ebuf[p2] = ((unsigned)s.z << BSH) | (unsigned)(d.z & (BSZ - 1));
            int p3 = atomicAdd(&lcur[d.w >> BSH], 1);
            ebuf[p3] = ((unsigned)s.w << BSH) | (unsigned)(d.w & (BSZ - 1));
        } else {
            for (int j = 0; j < 4; ++j) {
                if (e + j < E) {
                    int d = dst[e + j];
                    int p = atomicAdd(&lcur[d >> BSH], 1);
                    ebuf[p] = ((unsigned)src[e + j] << BSH) | (unsigned)(d & (BSZ - 1));
                }
            }
        }
    }
}

// ---------------- bfill: per-bucket node histogram + block scan -> rowptr, then col scatter ----------------

__launch_bounds__(256)
__global__ void k_bfill(const unsigned* __restrict__ ebufx, const unsigned* __restrict__ ebufy,
                        const int* __restrict__ boff,
                        int* __restrict__ rowx, int* __restrict__ rowy,
                        int* __restrict__ colx, int* __restrict__ coly,
                        int N, int NB, int E) {
    __shared__ int lh[BSZ];
    __shared__ int cur[BSZ];
    __shared__ int wsum[4];
    int b = blockIdx.x;
    int h = b >= NB;
    int b2 = b - h * NB;
    const unsigned* ebuf = h ? ebufy : ebufx;
    const int* bo = boff + h * NB;
    int* rowptr = h ? rowy : rowx;
    int* colarr = h ? coly : colx;
    int tid = threadIdx.x;
    int nbase = b2 << BSH;
    int ncnt = min(BSZ, N - nbase);
    for (int i = tid; i < BSZ; i += 256) lh[i] = 0;
    __syncthreads();
    int lo = bo[b2];
    int hi = (b2 + 1 < NB ? bo[b2 + 1] : E);
    // pass A: per-node histogram
    for (int j = lo + tid; j < hi; j += 256)
        atomicAdd(&lh[ebuf[j] & (BSZ - 1)], 1);
    __syncthreads();
    // block exclusive scan of 512 counts (2 per thread)
    int a = lh[tid * 2], bb = lh[tid * 2 + 1];
    int pair = a + bb;
    int incl = pair;
    int lane = tid & 63, w = tid >> 6;
    #pragma unroll
    for (int off = 1; off < 64; off <<= 1) {
        int t = __shfl_up(incl, off);
        if (lane >= off) incl += t;
    }
    if (lane == 63) wsum[w] = incl;
    __syncthreads();
    int wb = 0;
    for (int ww = 0; ww < w; ++ww) wb += wsum[ww];
    int ex = lo + wb + incl - pair;
    cur[tid * 2] = ex;
    cur[tid * 2 + 1] = ex + a;
    if (tid * 2 < ncnt)     rowptr[nbase + tid * 2] = ex;
    if (tid * 2 + 1 < ncnt) rowptr[nbase + tid * 2 + 1] = ex + a;
    if (tid == 0 && nbase + BSZ >= N) rowptr[N] = E;
    __syncthreads();
    // pass B: col scatter (localized ~bucket region)
    for (int j = lo + tid; j < hi; j += 256) {
        unsigned u = ebuf[j];
        int d = u & (BSZ - 1);
        int pos = atomicAdd(&cur[d], 1);
        colarr[pos] = (int)(u >> BSH);
    }
}

// ---------------- fused conv (both graphs in one grid): steal-balanced agg -> LDS ----------------
// -> MFMA + BN + ReLU -> store + fused global_add_pool.

#define ACC8(U) { acc[0] += bf_lo(U.x); acc[1] += bf_hi(U.x); \
                  acc[2] += bf_lo(U.y); acc[3] += bf_hi(U.y); \
                  acc[4] += bf_lo(U.z); acc[5] += bf_hi(U.z); \
                  acc[6] += bf_lo(U.w); acc[7] += bf_hi(U.w); }

__launch_bounds__(512)
__global__ void k_conv(const unsigned short* __restrict__ in0, const unsigned short* __restrict__ in1,
                       const int* __restrict__ rowx, const int* __restrict__ rowy,
                       const int* __restrict__ colx, const int* __restrict__ coly,
                       const unsigned short* __restrict__ Wt,
                       const float* __restrict__ convB, const float* __restrict__ gma,
                       const float* __restrict__ bta, const float* __restrict__ mea,
                       const float* __restrict__ varr,
                       const int* __restrict__ batch, float* __restrict__ pooled,
                       unsigned short* __restrict__ out0, unsigned short* __restrict__ out1,
                       int base, int GB, int N) {
    __shared__ unsigned short AL[64 * 128];    // 16 KB
    __shared__ int nextrow;
    int bid = blockIdx.x;
    int h = bid >= GB;
    int b2 = bid - h * GB;
    const unsigned short* inb = h ? in1 : in0;
    const int* rowptr = h ? rowy : rowx;
    const int* col = h ? coly : colx;
    unsigned short* outb = h ? out1 : out0;
    int idx = base + 2 * h;                    // weight/BN/pool-section index
    const unsigned short* Wk = Wt + idx * NCH * NCH;

    int tid = threadIdx.x;
    if (tid == 0) nextrow = 0;
    __syncthreads();

    const uint4* in16 = (const uint4*)inb;
    int lane = tid & 63;
    int l = lane & 15;
    int leader = lane & 48;                    // group leader lane within wave

    for (;;) {
        int rl = 0;
        if (l == 0) rl = atomicAdd(&nextrow, 1);
        rl = __shfl(rl, leader);
        if (rl >= 64) break;
        int row = b2 * 64 + rl;
        uint4 o = make_uint4(0, 0, 0, 0);
        if (row < N) {
            float acc[8];
            uint4 v = in16[(long)row * 16 + l];
            acc[0] = bf_lo(v.x); acc[1] = bf_hi(v.x);
            acc[2] = bf_lo(v.y); acc[3] = bf_hi(v.y);
            acc[4] = bf_lo(v.z); acc[5] = bf_hi(v.z);
            acc[6] = bf_lo(v.w); acc[7] = bf_hi(v.w);
            int beg = rowptr[row], end = rowptr[row + 1];
            if (beg < end) {
                int e1 = end - 1;
                int s0 = col[beg], s1 = col[min(beg + 1, e1)],
                    s2 = col[min(beg + 2, e1)], s3 = col[min(beg + 3, e1)];
                for (int j = beg; j < end; j += 4) {
                    int t0 = s0, t1 = s1, t2 = s2, t3 = s3;
                    int jn = j + 4;
                    if (jn < end) {                 // prefetch next col quad
                        s0 = col[jn];
                        s1 = col[min(jn + 1, e1)];
                        s2 = col[min(jn + 2, e1)];
                        s3 = col[min(jn + 3, e1)];
                    }
                    uint4 u0 = in16[(long)t0 * 16 + l];
                    uint4 u1 = in16[(long)t1 * 16 + l];
                    uint4 u2 = in16[(long)t2 * 16 + l];
                    uint4 u3 = in16[(long)t3 * 16 + l];
                    ACC8(u0);
                    if (j + 1 < end) ACC8(u1);
                    if (j + 2 < end) ACC8(u2);
                    if (j + 3 < end) ACC8(u3);
                }
            }
            o.x = (unsigned)f2bf(acc[0]) | ((unsigned)f2bf(acc[1]) << 16);
            o.y = (unsigned)f2bf(acc[2]) | ((unsigned)f2bf(acc[3]) << 16);
            o.z = (unsigned)f2bf(acc[4]) | ((unsigned)f2bf(acc[5]) << 16);
            o.w = (unsigned)f2bf(acc[6]) | ((unsigned)f2bf(acc[7]) << 16);
        }
        *(uint4*)((char*)AL + rl * 256 + ((l ^ (rl & 15)) << 4)) = o;
    }
    __syncthreads();

    int wid = tid >> 6;
    int wr = wid & 3, wc = wid >> 2;
    int lr = lane & 15, lg = lane >> 4;
    f32x4 acc[4] = {};
    #pragma unroll
    for (int ks = 0; ks < 4; ++ks) {
        short8v a = *(const short8v*)((char*)AL + (wr * 16 + lr) * 256 + (((ks * 4 + lg) ^ lr) << 4));
        #pragma unroll
        for (int c = 0; c < 4; ++c) {
            int n = (wc * 4 + c) * 16 + lr;
            short8v bfr = *(const short8v*)(Wk + n * 128 + ks * 32 + lg * 8);
            acc[c] = __builtin_amdgcn_mfma_f32_16x16x32_bf16(a, bfr, acc[c], 0, 0, 0);
        }
    }

    // epilogue: BN + ReLU, store bf16, fused pool (rows are 4 consecutive -> few runs)
    int rowbase = b2 * 64 + wr * 16 + lg * 4;
    int gv[4];
    #pragma unroll
    for (int r = 0; r < 4; ++r) gv[r] = (rowbase + r < N) ? batch[rowbase + r] : -1;

    #pragma unroll
    for (int c = 0; c < 4; ++c) {
        int colc = (wc * 4 + c) * 16 + lr;
        float s = gma[idx * NCH + colc] * rsqrtf(varr[idx * NCH + colc] + 1e-5f);
        float sh = (convB[idx * NCH + colc] - mea[idx * NCH + colc]) * s + bta[idx * NCH + colc];
        float vr[4];
        #pragma unroll
        for (int r = 0; r < 4; ++r) {
            int row = rowbase + r;
            if (row < N) {
                float v = fmaxf(acc[c][r] * s + sh, 0.f);
                outb[(long)row * NCH + colc] = f2bf(v);
                vr[r] = v;
            } else vr[r] = 0.f;
        }
        float sum = 0.f;
        int gprev = gv[0];
        #pragma unroll
        for (int r = 0; r < 4; ++r) {
            if (gv[r] != gprev) {
                if (gprev >= 0) atomicAdd(&pooled[gprev * 512 + idx * 128 + colc], sum);
                gprev = gv[r];
                sum = 0.f;
            }
            sum += vr[r];
        }
        if (gprev >= 0) atomicAdd(&pooled[gprev * 512 + idx * 128 + colc], sum);
    }
}

// ---------------- MLP head + log_softmax ----------------

__launch_bounds__(256)
__global__ void k_mlp(const float* __restrict__ pooled,
                      const float* __restrict__ w1, const float* __restrict__ b1,
                      const float* __restrict__ w2, const float* __restrict__ b2,
                      float* __restrict__ out) {
    __shared__ float row[512];
    __shared__ float hid[256];
    __shared__ float o10[10];
    int g = blockIdx.x, tid = threadIdx.x;
    row[tid] = pooled[g * 512 + tid];
    row[tid + 256] = pooled[g * 512 + 256 + tid];
    __syncthreads();
    float acc = b1[tid];
    for (int k = 0; k < 512; ++k) acc += row[k] * w1[k * 256 + tid];
    hid[tid] = fmaxf(acc, 0.f);
    __syncthreads();
    if (tid < 10) {
        float o = b2[tid];
        for (int k = 0; k < 256; ++k) o += hid[k] * w2[k * 10 + tid];
        o10[tid] = o;
        out[g * 10 + tid] = o;
    }
    __syncthreads();
    if (tid == 0) {
        float m = o10[0];
        for (int j = 1; j < 10; ++j) m = fmaxf(m, o10[j]);
        float s = 0.f;
        for (int j = 0; j < 10; ++j) s += expf(o10[j] - m);
        float ls = m + logf(s);
        for (int j = 0; j < 10; ++j) out[NGRAPH * 10 + g * 10 + j] = o10[j] - ls;
    }
}

// ---------------- launch ----------------

extern "C" void kernel_launch(void* const* d_in, const int* in_sizes, int n_in,
                              void* d_out, int out_size, void* d_ws, size_t ws_size,
                              hipStream_t stream) {
    const float* x     = (const float*)d_in[0];
    const int*   eix   = (const int*)d_in[1];
    const int*   eiy   = (const int*)d_in[2];
    const int*   batch = (const int*)d_in[3];
    const float* convW = (const float*)d_in[4];
    const float* convB = (const float*)d_in[5];
    const float* gma   = (const float*)d_in[6];
    const float* bta   = (const float*)d_in[7];
    const float* mea   = (const float*)d_in[8];
    const float* var   = (const float*)d_in[9];
    const float* w1    = (const float*)d_in[10];
    const float* b1    = (const float*)d_in[11];
    const float* w2    = (const float*)d_in[12];
    const float* b2    = (const float*)d_in[13];
    float* out = (float*)d_out;

    int N = in_sizes[0] / NCH;
    int E = in_sizes[1] / 2;
    int NB = (N + BSZ - 1) >> BSH;   // dst buckets per set

    char* p = (char*)d_ws;
    auto alloc = [&](size_t bytes) {
        char* r = p;
        p += (bytes + 255) & ~(size_t)255;
        return r;
    };
    int* rowx      = (int*)alloc((size_t)(N + 1) * 4);
    int* rowy      = (int*)alloc((size_t)(N + 1) * 4);
    int* colx      = (int*)alloc((size_t)E * 4);
    int* coly      = (int*)alloc((size_t)E * 4);
    int* bghist    = (int*)alloc((size_t)2 * NB * 4);
    int* boff      = (int*)alloc((size_t)2 * NB * 4);
    int* bcur      = (int*)alloc((size_t)2 * NB * 4);
    unsigned* ebufx = (unsigned*)alloc((size_t)E * 4);
    unsigned* ebufy = (unsigned*)alloc((size_t)E * 4);
    unsigned short* xb   = (unsigned short*)alloc((size_t)N * NCH * 2);
    unsigned short* Wt   = (unsigned short*)alloc((size_t)4 * NCH * NCH * 2);
    unsigned short* bufA = (unsigned short*)alloc((size_t)N * NCH * 2);
    unsigned short* bufB = (unsigned short*)alloc((size_t)N * NCH * 2);
    unsigned short* bufC = (unsigned short*)alloc((size_t)N * NCH * 2);
    unsigned short* bufD = (unsigned short*)alloc((size_t)N * NCH * 2);
    float* pooled = (float*)alloc((size_t)NGRAPH * 512 * 4);

    const int* srcx = eix;
    const int* dstx = eix + E;
    const int* srcy = eiy;
    const int* dsty = eiy + E;

    int SB = (E + 4095) / 4096;
    int GB = (N + 63) / 64;
    size_t lds_b = (size_t)NB * 4;

    hipMemsetAsync(bghist, 0, (size_t)2 * NB * 4, stream);
    hipMemsetAsync(pooled, 0, (size_t)NGRAPH * 512 * 4, stream);

    k_prep<<<2304, 256, 0, stream>>>(convW, Wt, x, xb, (long)N * 32);
    k_bhist<<<2 * SB, 256, lds_b, stream>>>(dstx, dsty, bghist, E, SB, NB);
    k_bhscan<<<1, 128, 0, stream>>>(bghist, boff, bcur, NB);
    k_bscatter<<<2 * SB, 256, lds_b, stream>>>(srcx, dstx, srcy, dsty, bcur, ebufx, ebufy, E, SB, NB);
    k_bfill<<<2 * NB, 256, 0, stream>>>(ebufx, ebufy, boff, rowx, rowy, colx, coly, N, NB, E);

    // conv1: x-graph (idx0) -> bufA, y-graph (idx2) -> bufC, pool secs 0/2
    k_conv<<<2 * GB, 512, 0, stream>>>(xb, xb, rowx, rowy, colx, coly, Wt, convB, gma, bta, mea, var,
                                       batch, pooled, bufA, bufC, 0, GB, N);
    // conv2: bufA (idx1) -> bufB, bufC (idx3) -> bufD, pool secs 1/3
    k_conv<<<2 * GB, 512, 0, stream>>>(bufA, bufC, rowx, rowy, colx, coly, Wt, convB, gma, bta, mea, var,
                                       batch, pooled, bufB, bufD, 1, GB, N);

    k_mlp<<<NGRAPH, 256, 0, stream>>>(pooled, w1, b1, w2, b2, out);
}

// Round 8
// 583.239 us; speedup vs baseline: 2.5087x; 1.0849x over previous
//
#include <hip/hip_runtime.h>
#include <math.h>

#define NCH 128
#define NGRAPH 128
#define BSH 9                 // bucket shift: 512 nodes per bucket
#define BSZ (1 << BSH)

typedef __attribute__((ext_vector_type(8))) short short8v;
typedef __attribute__((ext_vector_type(4))) float f32x4;

static __device__ __forceinline__ float bf_lo(unsigned u) { return __uint_as_float(u << 16); }
static __device__ __forceinline__ float bf_hi(unsigned u) { return __uint_as_float(u & 0xffff0000u); }
static __device__ __forceinline__ unsigned short f2bf(float f) {
    unsigned u = __float_as_uint(f);
    return (unsigned short)((u + 0x7fffu + ((u >> 16) & 1u)) >> 16);
}

// ---------------- prep: blocks [0,256) transpose W -> bf16; rest convert x -> bf16 ----------------

__global__ void k_prep(const float* __restrict__ W, unsigned short* __restrict__ Wt,
                       const float* __restrict__ x, unsigned short* __restrict__ xb, long n4) {
    int b = blockIdx.x;
    if (b < 256) {
        int idx = b * 256 + threadIdx.x;   // 65536 = 4*128*128
        int i = idx >> 14, rem = idx & 16383;
        int n = rem >> 7, k = rem & 127;
        Wt[idx] = f2bf(W[i * 16384 + k * 128 + n]);
    } else {
        long i = (long)(b - 256) * 256 + threadIdx.x;
        long stride = 2048L * 256;
        for (; i < n4; i += stride) {
            float4 v = *(const float4*)(x + i * 4);
            ushort4 o;
            o.x = f2bf(v.x); o.y = f2bf(v.y); o.z = f2bf(v.z); o.w = f2bf(v.w);
            *(ushort4*)(xb + i * 4) = o;
        }
    }
}

// ---------------- bucket histogram (both edge sets; LDS-privatized) ----------------

__global__ void k_bhist(const int* __restrict__ dstx, const int* __restrict__ dsty,
                        int* __restrict__ bghist, int E, int SB, int NB) {
    extern __shared__ int lh[];            // NB ints
    int b = blockIdx.x;
    int h = b >= SB;
    const int* dst = h ? dsty : dstx;
    int* gh = bghist + h * NB;
    int b2 = b - h * SB;
    int tid = threadIdx.x;
    for (int i = tid; i < NB; i += 256) lh[i] = 0;
    __syncthreads();
    int e0 = b2 * 4096;
    #pragma unroll
    for (int i = 0; i < 4; ++i) {
        int e = e0 + i * 1024 + tid * 4;
        if (e + 3 < E) {
            int4 d = *(const int4*)(dst + e);
            atomicAdd(&lh[d.x >> BSH], 1);
            atomicAdd(&lh[d.y >> BSH], 1);
            atomicAdd(&lh[d.z >> BSH], 1);
            atomicAdd(&lh[d.w >> BSH], 1);
        } else {
            for (int j = 0; j < 4; ++j)
                if (e + j < E) atomicAdd(&lh[dst[e + j] >> BSH], 1);
        }
    }
    __syncthreads();
    for (int i = tid; i < NB; i += 256) {
        int c = lh[i];
        if (c) atomicAdd(&gh[i], c);
    }
}

// ---------------- scan bucket counts -> boff (preserved) and bcur (working) ----------------

__global__ void k_bhscan(const int* __restrict__ bghist, int* __restrict__ boff,
                         int* __restrict__ bcur, int NB) {
    int w = threadIdx.x >> 6, lane = threadIdx.x & 63;
    if (w < 2) {
        const int* hh = bghist + w * NB;
        int* bo = boff + w * NB;
        int* bc = bcur + w * NB;
        int carry = 0;
        for (int base = 0; base < NB; base += 64) {
            int v = (base + lane < NB) ? hh[base + lane] : 0;
            int incl = v;
            #pragma unroll
            for (int off = 1; off < 64; off <<= 1) {
                int t = __shfl_up(incl, off);
                if (lane >= off) incl += t;
            }
            if (base + lane < NB) {
                int ex = carry + incl - v;
                bo[base + lane] = ex;
                bc[base + lane] = ex;
            }
            carry += __shfl(incl, 63);
        }
    }
}

// ---------------- ranked bucket scatter (both sets; LDS-privatized) ----------------

__global__ void k_bscatter(const int* __restrict__ srcx, const int* __restrict__ dstx,
                           const int* __restrict__ srcy, const int* __restrict__ dsty,
                           int* __restrict__ bcur, unsigned* __restrict__ ebufx,
                           unsigned* __restrict__ ebufy, int E, int SB, int NB) {
    extern __shared__ int lcur[];          // NB ints
    int b = blockIdx.x;
    int h = b >= SB;
    int b2 = b - h * SB;
    const int* src = h ? srcy : srcx;
    const int* dst = h ? dsty : dstx;
    int* bc = bcur + h * NB;
    unsigned* ebuf = h ? ebufy : ebufx;
    int tid = threadIdx.x;
    int e0 = b2 * 4096;
    for (int i = tid; i < NB; i += 256) lcur[i] = 0;
    __syncthreads();
    #pragma unroll
    for (int i = 0; i < 4; ++i) {
        int e = e0 + i * 1024 + tid * 4;
        if (e + 3 < E) {
            int4 d = *(const int4*)(dst + e);
            atomicAdd(&lcur[d.x >> BSH], 1);
            atomicAdd(&lcur[d.y >> BSH], 1);
            atomicAdd(&lcur[d.z >> BSH], 1);
            atomicAdd(&lcur[d.w >> BSH], 1);
        } else {
            for (int j = 0; j < 4; ++j)
                if (e + j < E) atomicAdd(&lcur[dst[e + j] >> BSH], 1);
        }
    }
    __syncthreads();
    for (int i = tid; i < NB; i += 256) {
        int c = lcur[i];
        lcur[i] = c ? atomicAdd(&bc[i], c) : 0;
    }
    __syncthreads();
    #pragma unroll
    for (int i = 0; i < 4; ++i) {
        int e = e0 + i * 1024 + tid * 4;
        if (e + 3 < E) {
            int4 d = *(const int4*)(dst + e);
            int4 s = *(const int4*)(src + e);
            int p0 = atomicAdd(&lcur[d.x >> BSH], 1);
            ebuf[p0] = ((unsigned)s.x << BSH) | (unsigned)(d.x & (BSZ - 1));
            int p1 = atomicAdd(&lcur[d.y >> BSH], 1);
            ebuf[p1] = ((unsigned)s.y << BSH) | (unsigned)(d.y & (BSZ - 1));
            int p2 = atomicAdd(&lcur[d.z >> BSH], 1);
            ebuf[p2] = ((unsigned)s.z << BSH) | (unsigned)(d.z & (BSZ - 1));
            int p3 = atomicAdd(&lcur[d.w >> BSH], 1);
            ebuf[p3] = ((unsigned)s.w << BSH) | (unsigned)(d.w & (BSZ - 1));
        } else {
            for (int j = 0; j < 4; ++j) {
                if (e + j < E) {
                    int d = dst[e + j];
                    int p = atomicAdd(&lcur[d >> BSH], 1);
                    ebuf[p] = ((unsigned)src[e + j] << BSH) | (unsigned)(d & (BSZ - 1));
                }
            }
        }
    }
}

// ---------------- bfill: per-bucket node histogram + block scan -> rowptr, then col scatter ----------------

__launch_bounds__(256)
__global__ void k_bfill(const unsigned* __restrict__ ebufx, const unsigned* __restrict__ ebufy,
                        const int* __restrict__ boff,
                        int* __restrict__ rowx, int* __restrict__ rowy,
                        int* __restrict__ colx, int* __restrict__ coly,
                        int N, int NB, int E) {
    __shared__ int lh[BSZ];
    __shared__ int cur[BSZ];
    __shared__ int wsum[4];
    int b = blockIdx.x;
    int h = b >= NB;
    int b2 = b - h * NB;
    const unsigned* ebuf = h ? ebufy : ebufx;
    const int* bo = boff + h * NB;
    int* rowptr = h ? rowy : rowx;
    int* colarr = h ? coly : colx;
    int tid = threadIdx.x;
    int nbase = b2 << BSH;
    int ncnt = min(BSZ, N - nbase);
    for (int i = tid; i < BSZ; i += 256) lh[i] = 0;
    __syncthreads();
    int lo = bo[b2];
    int hi = (b2 + 1 < NB ? bo[b2 + 1] : E);
    for (int j = lo + tid; j < hi; j += 256)
        atomicAdd(&lh[ebuf[j] & (BSZ - 1)], 1);
    __syncthreads();
    int a = lh[tid * 2], bb = lh[tid * 2 + 1];
    int pair = a + bb;
    int incl = pair;
    int lane = tid & 63, w = tid >> 6;
    #pragma unroll
    for (int off = 1; off < 64; off <<= 1) {
        int t = __shfl_up(incl, off);
        if (lane >= off) incl += t;
    }
    if (lane == 63) wsum[w] = incl;
    __syncthreads();
    int wb = 0;
    for (int ww = 0; ww < w; ++ww) wb += wsum[ww];
    int ex = lo + wb + incl - pair;
    cur[tid * 2] = ex;
    cur[tid * 2 + 1] = ex + a;
    if (tid * 2 < ncnt)     rowptr[nbase + tid * 2] = ex;
    if (tid * 2 + 1 < ncnt) rowptr[nbase + tid * 2 + 1] = ex + a;
    if (tid == 0 && nbase + BSZ >= N) rowptr[N] = E;
    __syncthreads();
    for (int j = lo + tid; j < hi; j += 256) {
        unsigned u = ebuf[j];
        int d = u & (BSZ - 1);
        int pos = atomicAdd(&cur[d], 1);
        colarr[pos] = (int)(u >> BSH);
    }
}

// ---------------- fused conv (both graphs in one grid): round-5 gather -> LDS ----------------
// -> MFMA + BN + ReLU -> store + LDS-staged global_add_pool.

#define ACC8(U) { acc[0] += bf_lo(U.x); acc[1] += bf_hi(U.x); \
                  acc[2] += bf_lo(U.y); acc[3] += bf_hi(U.y); \
                  acc[4] += bf_lo(U.z); acc[5] += bf_hi(U.z); \
                  acc[6] += bf_lo(U.w); acc[7] += bf_hi(U.w); }

__launch_bounds__(512)
__global__ void k_conv(const unsigned short* __restrict__ in0, const unsigned short* __restrict__ in1,
                       const int* __restrict__ rowx, const int* __restrict__ rowy,
                       const int* __restrict__ colx, const int* __restrict__ coly,
                       const unsigned short* __restrict__ Wt,
                       const float* __restrict__ convB, const float* __restrict__ gma,
                       const float* __restrict__ bta, const float* __restrict__ mea,
                       const float* __restrict__ varr,
                       const int* __restrict__ batch, float* __restrict__ pooled,
                       unsigned short* __restrict__ out0, unsigned short* __restrict__ out1,
                       int base, int GB, int N) {
    __shared__ unsigned short AL[64 * 128];    // 16 KB
    __shared__ float PL[8 * 128];              // 4 KB pool staging
    int bid = blockIdx.x;
    int h = bid >= GB;
    int b2 = bid - h * GB;
    const unsigned short* inb = h ? in1 : in0;
    const int* rowptr = h ? rowy : rowx;
    const int* col = h ? coly : colx;
    unsigned short* outb = h ? out1 : out0;
    int idx = base + 2 * h;                    // weight/BN/pool-section index
    const unsigned short* Wk = Wt + idx * NCH * NCH;

    int tid = threadIdx.x;
    for (int i = tid; i < 1024; i += 512) PL[i] = 0.f;

    const uint4* in16 = (const uint4*)inb;
    int l = tid & 15;
    #pragma unroll
    for (int rep = 0; rep < 2; ++rep) {
        int rl = rep * 32 + (tid >> 4);
        int row = b2 * 64 + rl;
        uint4 o = make_uint4(0, 0, 0, 0);
        if (row < N) {
            float acc[8];
            uint4 v = in16[(long)row * 16 + l];
            acc[0] = bf_lo(v.x); acc[1] = bf_hi(v.x);
            acc[2] = bf_lo(v.y); acc[3] = bf_hi(v.y);
            acc[4] = bf_lo(v.z); acc[5] = bf_hi(v.z);
            acc[6] = bf_lo(v.w); acc[7] = bf_hi(v.w);
            int beg = rowptr[row], end = rowptr[row + 1];
            int j = beg;
            for (; j + 4 <= end; j += 4) {
                int s0 = col[j + 0], s1 = col[j + 1], s2 = col[j + 2], s3 = col[j + 3];
                uint4 u0 = in16[(long)s0 * 16 + l];
                uint4 u1 = in16[(long)s1 * 16 + l];
                uint4 u2 = in16[(long)s2 * 16 + l];
                uint4 u3 = in16[(long)s3 * 16 + l];
                ACC8(u0); ACC8(u1); ACC8(u2); ACC8(u3);
            }
            for (; j < end; ++j) {
                int s = col[j];
                uint4 u = in16[(long)s * 16 + l];
                ACC8(u);
            }
            o.x = (unsigned)f2bf(acc[0]) | ((unsigned)f2bf(acc[1]) << 16);
            o.y = (unsigned)f2bf(acc[2]) | ((unsigned)f2bf(acc[3]) << 16);
            o.z = (unsigned)f2bf(acc[4]) | ((unsigned)f2bf(acc[5]) << 16);
            o.w = (unsigned)f2bf(acc[6]) | ((unsigned)f2bf(acc[7]) << 16);
        }
        *(uint4*)((char*)AL + rl * 256 + ((l ^ (rl & 15)) << 4)) = o;
    }
    __syncthreads();

    int wid = tid >> 6, lane = tid & 63;
    int wr = wid & 3, wc = wid >> 2;
    int lr = lane & 15, lg = lane >> 4;
    f32x4 acc[4] = {};
    #pragma unroll
    for (int ks = 0; ks < 4; ++ks) {
        short8v a = *(const short8v*)((char*)AL + (wr * 16 + lr) * 256 + (((ks * 4 + lg) ^ lr) << 4));
        #pragma unroll
        for (int c = 0; c < 4; ++c) {
            int n = (wc * 4 + c) * 16 + lr;
            short8v bfr = *(const short8v*)(Wk + n * 128 + ks * 32 + lg * 8);
            acc[c] = __builtin_amdgcn_mfma_f32_16x16x32_bf16(a, bfr, acc[c], 0, 0, 0);
        }
    }

    // epilogue: BN + ReLU, store bf16, pool into LDS (slot = graph - gbase)
    int rowbase = b2 * 64 + wr * 16 + lg * 4;
    int gbase = (b2 * 64 < N) ? batch[b2 * 64] : 0;
    int gv[4];
    #pragma unroll
    for (int r = 0; r < 4; ++r) gv[r] = (rowbase + r < N) ? batch[rowbase + r] : -1;

    #pragma unroll
    for (int c = 0; c < 4; ++c) {
        int colc = (wc * 4 + c) * 16 + lr;
        float s = gma[idx * NCH + colc] * rsqrtf(varr[idx * NCH + colc] + 1e-5f);
        float sh = (convB[idx * NCH + colc] - mea[idx * NCH + colc]) * s + bta[idx * NCH + colc];
        #pragma unroll
        for (int r = 0; r < 4; ++r) {
            int row = rowbase + r;
            if (row < N) {
                float v = fmaxf(acc[c][r] * s + sh, 0.f);
                outb[(long)row * NCH + colc] = f2bf(v);
                int slot = gv[r] - gbase;
                if ((unsigned)slot < 8u) atomicAdd(&PL[slot * 128 + colc], v);
                else atomicAdd(&pooled[gv[r] * 512 + idx * 128 + colc], v);
            }
        }
    }
    __syncthreads();
    for (int i = tid; i < 1024; i += 512) {
        float v = PL[i];
        int g = gbase + (i >> 7);
        if (v != 0.f && g < NGRAPH) atomicAdd(&pooled[g * 512 + idx * 128 + (i & 127)], v);
    }
}

// ---------------- MLP head + log_softmax ----------------

__launch_bounds__(256)
__global__ void k_mlp(const float* __restrict__ pooled,
                      const float* __restrict__ w1, const float* __restrict__ b1,
                      const float* __restrict__ w2, const float* __restrict__ b2,
                      float* __restrict__ out) {
    __shared__ float row[512];
    __shared__ float hid[256];
    __shared__ float o10[10];
    int g = blockIdx.x, tid = threadIdx.x;
    row[tid] = pooled[g * 512 + tid];
    row[tid + 256] = pooled[g * 512 + 256 + tid];
    __syncthreads();
    float acc = b1[tid];
    for (int k = 0; k < 512; ++k) acc += row[k] * w1[k * 256 + tid];
    hid[tid] = fmaxf(acc, 0.f);
    __syncthreads();
    if (tid < 10) {
        float o = b2[tid];
        for (int k = 0; k < 256; ++k) o += hid[k] * w2[k * 10 + tid];
        o10[tid] = o;
        out[g * 10 + tid] = o;
    }
    __syncthreads();
    if (tid == 0) {
        float m = o10[0];
        for (int j = 1; j < 10; ++j) m = fmaxf(m, o10[j]);
        float s = 0.f;
        for (int j = 0; j < 10; ++j) s += expf(o10[j] - m);
        float ls = m + logf(s);
        for (int j = 0; j < 10; ++j) out[NGRAPH * 10 + g * 10 + j] = o10[j] - ls;
    }
}

// ---------------- launch ----------------

extern "C" void kernel_launch(void* const* d_in, const int* in_sizes, int n_in,
                              void* d_out, int out_size, void* d_ws, size_t ws_size,
                              hipStream_t stream) {
    const float* x     = (const float*)d_in[0];
    const int*   eix   = (const int*)d_in[1];
    const int*   eiy   = (const int*)d_in[2];
    const int*   batch = (const int*)d_in[3];
    const float* convW = (const float*)d_in[4];
    const float* convB = (const float*)d_in[5];
    const float* gma   = (const float*)d_in[6];
    const float* bta   = (const float*)d_in[7];
    const float* mea   = (const float*)d_in[8];
    const float* var   = (const float*)d_in[9];
    const float* w1    = (const float*)d_in[10];
    const float* b1    = (const float*)d_in[11];
    const float* w2    = (const float*)d_in[12];
    const float* b2    = (const float*)d_in[13];
    float* out = (float*)d_out;

    int N = in_sizes[0] / NCH;
    int E = in_sizes[1] / 2;
    int NB = (N + BSZ - 1) >> BSH;   // dst buckets per set

    char* p = (char*)d_ws;
    auto alloc = [&](size_t bytes) {
        char* r = p;
        p += (bytes + 255) & ~(size_t)255;
        return r;
    };
    int* rowx      = (int*)alloc((size_t)(N + 1) * 4);
    int* rowy      = (int*)alloc((size_t)(N + 1) * 4);
    int* colx      = (int*)alloc((size_t)E * 4);
    int* coly      = (int*)alloc((size_t)E * 4);
    int* bghist    = (int*)alloc((size_t)2 * NB * 4);
    int* boff      = (int*)alloc((size_t)2 * NB * 4);
    int* bcur      = (int*)alloc((size_t)2 * NB * 4);
    unsigned* ebufx = (unsigned*)alloc((size_t)E * 4);
    unsigned* ebufy = (unsigned*)alloc((size_t)E * 4);
    unsigned short* xb   = (unsigned short*)alloc((size_t)N * NCH * 2);
    unsigned short* Wt   = (unsigned short*)alloc((size_t)4 * NCH * NCH * 2);
    unsigned short* bufA = (unsigned short*)alloc((size_t)N * NCH * 2);
    unsigned short* bufB = (unsigned short*)alloc((size_t)N * NCH * 2);
    unsigned short* bufC = (unsigned short*)alloc((size_t)N * NCH * 2);
    unsigned short* bufD = (unsigned short*)alloc((size_t)N * NCH * 2);
    float* pooled = (float*)alloc((size_t)NGRAPH * 512 * 4);

    const int* srcx = eix;
    const int* dstx = eix + E;
    const int* srcy = eiy;
    const int* dsty = eiy + E;

    int SB = (E + 4095) / 4096;
    int GB = (N + 63) / 64;
    size_t lds_b = (size_t)NB * 4;

    hipMemsetAsync(bghist, 0, (size_t)2 * NB * 4, stream);
    hipMemsetAsync(pooled, 0, (size_t)NGRAPH * 512 * 4, stream);

    k_prep<<<2304, 256, 0, stream>>>(convW, Wt, x, xb, (long)N * 32);
    k_bhist<<<2 * SB, 256, lds_b, stream>>>(dstx, dsty, bghist, E, SB, NB);
    k_bhscan<<<1, 128, 0, stream>>>(bghist, boff, bcur, NB);
    k_bscatter<<<2 * SB, 256, lds_b, stream>>>(srcx, dstx, srcy, dsty, bcur, ebufx, ebufy, E, SB, NB);
    k_bfill<<<2 * NB, 256, 0, stream>>>(ebufx, ebufy, boff, rowx, rowy, colx, coly, N, NB, E);

    // conv1: x-graph (idx0) -> bufA, y-graph (idx2) -> bufC, pool secs 0/2
    k_conv<<<2 * GB, 512, 0, stream>>>(xb, xb, rowx, rowy, colx, coly, Wt, convB, gma, bta, mea, var,
                                       batch, pooled, bufA, bufC, 0, GB, N);
    // conv2: bufA (idx1) -> bufB, bufC (idx3) -> bufD, pool secs 1/3
    k_conv<<<2 * GB, 512, 0, stream>>>(bufA, bufC, rowx, rowy, colx, coly, Wt, convB, gma, bta, mea, var,
                                       batch, pooled, bufB, bufD, 1, GB, N);

    k_mlp<<<NGRAPH, 256, 0, stream>>>(pooled, w1, b1, w2, b2, out);
}